// Round 4
// baseline (747.666 us; speedup 1.0000x reference)
//
#include <hip/hip_runtime.h>
#include <hip/hip_bf16.h>
#include <stdint.h>

#define SEQ    2048
#define DMODEL 4096
#define NH     32
#define NKVH   8
#define HDIM   128
#define KVD    (NKVH*HDIM)   // 1024
#define QD     (NH*HDIM)     // 4096
#define ASCALE 0.08838834764831845f

typedef __attribute__((ext_vector_type(8))) short s8v;   // 8 bf16
typedef __attribute__((ext_vector_type(4))) short s4v;   // 4 bf16
typedef __attribute__((ext_vector_type(4))) float f4v;   // 4 f32

#define MFMA16(acc, a, b) \
  asm("v_mfma_f32_16x16x32_bf16 %0, %1, %2, %0" : "+v"(acc) : "v"(a), "v"(b))

__device__ __forceinline__ void gl2lds16(const void* g, void* l) {
  __builtin_amdgcn_global_load_lds(
      (const __attribute__((address_space(1))) void*)g,
      (__attribute__((address_space(3))) void*)l, 16, 0, 0);
}

__device__ __forceinline__ void store_out(__hip_bfloat16* p, float v) { *p = __float2bfloat16(v); }
__device__ __forceinline__ void store_out(float* p, float v) { *p = v; }

// ---------------- f32 -> bf16 convert ----------------
__global__ __launch_bounds__(256) void k_cvt(const float* __restrict__ in,
                                             __hip_bfloat16* __restrict__ out, int n8) {
  int i = blockIdx.x * 256 + threadIdx.x;
  if (i >= n8) return;
  const float4* p = (const float4*)in + (size_t)i * 2;
  float4 a = p[0], b = p[1];
  union { __hip_bfloat16 h[8]; s8v v; } o;
  o.h[0] = __float2bfloat16(a.x); o.h[1] = __float2bfloat16(a.y);
  o.h[2] = __float2bfloat16(a.z); o.h[3] = __float2bfloat16(a.w);
  o.h[4] = __float2bfloat16(b.x); o.h[5] = __float2bfloat16(b.y);
  o.h[6] = __float2bfloat16(b.z); o.h[7] = __float2bfloat16(b.w);
  *(s8v*)(out + (size_t)i * 8) = o.v;
}

// ---------------- RoPE in-place on bf16 ----------------
__global__ __launch_bounds__(256) void k_rope(__hip_bfloat16* __restrict__ t,
                                              const float* __restrict__ fc,
                                              const float* __restrict__ fs, int heads) {
  int pid = blockIdx.x * 256 + threadIdx.x;
  int i = pid & 63;
  int rest = pid >> 6;
  int h = rest % heads;
  int s = rest / heads;
  size_t base = ((size_t)s * heads + h) * HDIM + 2 * i;
  uint32_t u = *(const uint32_t*)(t + base);
  __hip_bfloat16 hh[2]; *(uint32_t*)hh = u;
  float tr = __bfloat162float(hh[0]), ti = __bfloat162float(hh[1]);
  float c = fc[(size_t)s * 64 + i], sv = fs[(size_t)s * 64 + i];
  hh[0] = __float2bfloat16(tr * c - ti * sv);
  hh[1] = __float2bfloat16(tr * sv + ti * c);
  *(uint32_t*)(t + base) = *(uint32_t*)hh;
}

// ---------------- C = A(M,K) * B(N,K)^T (m97 structure, verified R1/R3) ----------------
template <typename OT>
__global__ __launch_bounds__(256) void k_gemm_bt(const __hip_bfloat16* __restrict__ A,
                                                 const __hip_bfloat16* __restrict__ B,
                                                 OT* __restrict__ C, int M, int N, int K) {
  __shared__ __align__(16) __hip_bfloat16 As[128 * 64];
  __shared__ __align__(16) __hip_bfloat16 Bs[128 * 64];
  const int t = threadIdx.x;
  const int wave = t >> 6, lane = t & 63;
  const int lrow = lane & 15, kq = lane >> 4;
  const int wr = wave >> 1, wc = wave & 1;
  const int m0 = blockIdx.y * 128, n0 = blockIdx.x * 128;

  f4v acc[4][4] = {};

  for (int k0 = 0; k0 < K; k0 += 64) {
#pragma unroll
    for (int it = 0; it < 4; ++it) {
      int chunk = it * 256 + t;
      int r = chunk >> 3;
      int cc = ((chunk & 7) ^ (r & 7)) * 8;
      gl2lds16(A + (size_t)(m0 + r) * K + k0 + cc, (char*)As + it * 4096 + wave * 1024);
      gl2lds16(B + (size_t)(n0 + r) * K + k0 + cc, (char*)Bs + it * 4096 + wave * 1024);
    }
    __syncthreads();
#pragma unroll
    for (int kk = 0; kk < 64; kk += 32) {
      s8v af[4], bfr[4];
#pragma unroll
      for (int m = 0; m < 4; ++m) {
        int row = wr * 64 + m * 16 + lrow;
        af[m] = *(const s8v*)&As[row * 64 + ((kk + kq * 8) ^ ((row & 7) << 3))];
      }
#pragma unroll
      for (int n = 0; n < 4; ++n) {
        int row = wc * 64 + n * 16 + lrow;
        bfr[n] = *(const s8v*)&Bs[row * 64 + ((kk + kq * 8) ^ ((row & 7) << 3))];
      }
#pragma unroll
      for (int m = 0; m < 4; ++m)
#pragma unroll
        for (int n = 0; n < 4; ++n)
          MFMA16(acc[m][n], af[m], bfr[n]);
    }
    __syncthreads();
  }

#pragma unroll
  for (int m = 0; m < 4; ++m)
#pragma unroll
    for (int n = 0; n < 4; ++n)
#pragma unroll
      for (int j = 0; j < 4; ++j) {
        int r = m0 + wr * 64 + m * 16 + kq * 4 + j;
        int c = n0 + wc * 64 + n * 16 + lrow;
        store_out(&C[(size_t)r * N + c], acc[m][n][j]);
      }
}

// ---------------- fused K+V projection: K row-major, V transposed (d-major) ----------------
__global__ __launch_bounds__(256) void k_gemm_kv(const __hip_bfloat16* __restrict__ A,
                                                 const __hip_bfloat16* __restrict__ Bk,
                                                 const __hip_bfloat16* __restrict__ Bv,
                                                 __hip_bfloat16* __restrict__ Ck,
                                                 __hip_bfloat16* __restrict__ Vt) {
  __shared__ __align__(16) __hip_bfloat16 As[128 * 64];
  __shared__ __align__(16) __hip_bfloat16 Bs[128 * 64];
  const int t = threadIdx.x;
  const int wave = t >> 6, lane = t & 63;
  const int lrow = lane & 15, kq = lane >> 4;
  const int wr = wave >> 1, wc = wave & 1;
  const int m0 = blockIdx.y * 128;
  const bool isV = blockIdx.x >= 8;
  const int n0 = (blockIdx.x & 7) * 128;
  const __hip_bfloat16* B = isV ? Bv : Bk;

  f4v acc[4][4] = {};

  for (int k0 = 0; k0 < DMODEL; k0 += 64) {
#pragma unroll
    for (int it = 0; it < 4; ++it) {
      int chunk = it * 256 + t;
      int r = chunk >> 3;
      int cc = ((chunk & 7) ^ (r & 7)) * 8;
      gl2lds16(A + (size_t)(m0 + r) * DMODEL + k0 + cc, (char*)As + it * 4096 + wave * 1024);
      gl2lds16(B + (size_t)(n0 + r) * DMODEL + k0 + cc, (char*)Bs + it * 4096 + wave * 1024);
    }
    __syncthreads();
#pragma unroll
    for (int kk = 0; kk < 64; kk += 32) {
      s8v af[4], bfr[4];
#pragma unroll
      for (int m = 0; m < 4; ++m) {
        int row = wr * 64 + m * 16 + lrow;
        af[m] = *(const s8v*)&As[row * 64 + ((kk + kq * 8) ^ ((row & 7) << 3))];
      }
#pragma unroll
      for (int n = 0; n < 4; ++n) {
        int row = wc * 64 + n * 16 + lrow;
        bfr[n] = *(const s8v*)&Bs[row * 64 + ((kk + kq * 8) ^ ((row & 7) << 3))];
      }
#pragma unroll
      for (int m = 0; m < 4; ++m)
#pragma unroll
        for (int n = 0; n < 4; ++n)
          MFMA16(acc[m][n], af[m], bfr[n]);
    }
    __syncthreads();
  }

  if (isV) {
    // transposed write: Vt[kv-dim c][s], 4 consecutive s per lane -> 8B stores
#pragma unroll
    for (int m = 0; m < 4; ++m)
#pragma unroll
      for (int n = 0; n < 4; ++n) {
        int c = n0 + wc * 64 + n * 16 + lrow;
        int r0 = m0 + wr * 64 + m * 16 + kq * 4;
        union { __hip_bfloat16 b[4]; s4v v; } u;
#pragma unroll
        for (int j = 0; j < 4; ++j) u.b[j] = __float2bfloat16(acc[m][n][j]);
        *(s4v*)&Vt[(size_t)c * SEQ + r0] = u.v;
      }
  } else {
#pragma unroll
    for (int m = 0; m < 4; ++m)
#pragma unroll
      for (int n = 0; n < 4; ++n)
#pragma unroll
        for (int j = 0; j < 4; ++j) {
          int r = m0 + wr * 64 + m * 16 + kq * 4 + j;
          int c = n0 + wc * 64 + n * 16 + lrow;
          Ck[(size_t)r * KVD + c] = __float2bfloat16(acc[m][n][j]);
        }
  }
}

// ---------------- causal flash attention ----------------
// One q-tile (64 rows) per block, 4 waves x 16 rows. Grid (32,NH), LPT order
// (qt = 31 - blockIdx.x so longest blocks dispatch first). Single K/V buffers:
// 40KB LDS -> 4 blocks/CU, 16 waves/CU; cross-block TLP hides staging latency
// (m114). Numerics identical to R3 except bit-exact rescale elision (fsc==1).
__global__ __launch_bounds__(256, 4) void k_flash(const __hip_bfloat16* __restrict__ Q,
                                                  const __hip_bfloat16* __restrict__ Kb,
                                                  const __hip_bfloat16* __restrict__ Vtg,
                                                  __hip_bfloat16* __restrict__ O) {
  __shared__ __align__(16) __hip_bfloat16 Ks[64 * 128];
  __shared__ __align__(16) __hip_bfloat16 Vs[128 * 64];
  __shared__ __align__(16) __hip_bfloat16 Ps[4][16 * 64];
  const int qt = 31 - blockIdx.x, h = blockIdx.y, g = h >> 2;
  const int t = threadIdx.x, wave = t >> 6, lane = t & 63;
  const int lrow = lane & 15, kq = lane >> 4;
  const int qrow = qt * 64 + wave * 16 + lrow;

  s8v qf[4];
#pragma unroll
  for (int tt = 0; tt < 4; ++tt)
    qf[tt] = *(const s8v*)(Q + (size_t)qrow * QD + h * HDIM + tt * 32 + kq * 8);

  f4v acc_o[8] = {};
  float mrun[4] = {-1e30f, -1e30f, -1e30f, -1e30f};
  float lrun[4] = {0.f, 0.f, 0.f, 0.f};

  for (int kv = 0; kv < qt + 1; ++kv) {
    if (kv) __syncthreads();          // all waves done reading Ks/Vs/Ps
    // stage K (64x128) and V^T (128x64), linear LDS dest + inverse-swz source
#pragma unroll
    for (int it = 0; it < 4; ++it) {
      int chunk = it * 256 + t;
      int r = chunk >> 4, cc = ((chunk & 15) ^ (r & 7)) * 8;
      gl2lds16(Kb + (size_t)(kv * 64 + r) * KVD + g * HDIM + cc,
               (char*)Ks + it * 4096 + wave * 1024);
    }
#pragma unroll
    for (int it = 0; it < 4; ++it) {
      int chunk = it * 256 + t;
      int d = chunk >> 3, cc = ((chunk & 7) ^ (d & 7)) * 8;
      gl2lds16(Vtg + (size_t)(g * HDIM + d) * SEQ + kv * 64 + cc,
               (char*)Vs + it * 4096 + wave * 1024);
    }
    __syncthreads();                  // staged (vmcnt drained before barrier)

    // S = Q * K^T   (16 q x 64 k per wave)
    f4v s[4] = {};
#pragma unroll
    for (int tt = 0; tt < 4; ++tt)
#pragma unroll
      for (int n = 0; n < 4; ++n) {
        int row = n * 16 + lrow;
        s8v kf = *(const s8v*)&Ks[row * 128 + ((tt * 32 + kq * 8) ^ ((row & 7) << 3))];
        MFMA16(s[n], qf[tt], kf);
      }

    // online softmax (R1-exact math; rescale elided only when fsc==1 exactly)
    __hip_bfloat16* P = &Ps[wave][0];
    asm volatile("" ::: "memory");
#pragma unroll
    for (int j = 0; j < 4; ++j) {
      const int qi = qt * 64 + wave * 16 + kq * 4 + j;
      float p4[4];
      float mx = -1e30f;
#pragma unroll
      for (int n = 0; n < 4; ++n) {
        int ki = kv * 64 + n * 16 + lrow;
        float v = (ki <= qi) ? s[n][j] * ASCALE : -1e30f;
        p4[n] = v;
        mx = fmaxf(mx, v);
      }
#pragma unroll
      for (int msk = 1; msk < 16; msk <<= 1) mx = fmaxf(mx, __shfl_xor(mx, msk, 64));
      if (!__all(mx <= mrun[j])) {    // new max somewhere -> rescale (else fsc==1, exact no-op)
        float mnew = fmaxf(mrun[j], mx);
        float fsc = __expf(mrun[j] - mnew);
        mrun[j] = mnew;
        lrun[j] *= fsc;
#pragma unroll
        for (int n = 0; n < 8; ++n) acc_o[n][j] *= fsc;
      }
      float rs = 0.f;
      const int drow = kq * 4 + j;
#pragma unroll
      for (int n = 0; n < 4; ++n) {
        float p = __expf(p4[n] - mrun[j]);
        rs += p;
        P[drow * 64 + ((n * 16 + lrow) ^ ((drow & 7) << 3))] = __float2bfloat16(p);
      }
#pragma unroll
      for (int msk = 1; msk < 16; msk <<= 1) rs += __shfl_xor(rs, msk, 64);
      lrun[j] += rs;
    }
    asm volatile("" ::: "memory");

    // O += P(16x64) * V(64x128)
#pragma unroll
    for (int tt = 0; tt < 2; ++tt) {
      s8v pa = *(const s8v*)&P[lrow * 64 + ((tt * 32 + kq * 8) ^ ((lrow & 7) << 3))];
#pragma unroll
      for (int n = 0; n < 8; ++n) {
        int d = n * 16 + lrow;
        s8v vf = *(const s8v*)&Vs[d * 64 + ((tt * 32 + kq * 8) ^ ((d & 7) << 3))];
        MFMA16(acc_o[n], pa, vf);
      }
    }
  }

#pragma unroll
  for (int n = 0; n < 8; ++n)
#pragma unroll
    for (int j = 0; j < 4; ++j) {
      int d = n * 16 + lrow;
      int qi = qt * 64 + wave * 16 + kq * 4 + j;
      O[(size_t)qi * QD + h * HDIM + d] = __float2bfloat16(acc_o[n][j] / lrun[j]);
    }
}

// ---------------- launch ----------------
extern "C" void kernel_launch(void* const* d_in, const int* in_sizes, int n_in,
                              void* d_out, int out_size, void* d_ws, size_t ws_size,
                              hipStream_t stream) {
  const float* x  = (const float*)d_in[0];
  const float* fc = (const float*)d_in[1];
  const float* fs = (const float*)d_in[2];
  const float* wq = (const float*)d_in[3];
  const float* wk = (const float*)d_in[4];
  const float* wv = (const float*)d_in[5];
  const float* wo = (const float*)d_in[6];
  float* out = (float*)d_out;

  char* ws = (char*)d_ws;
  auto alloc = [&](size_t bytes) {
    char* p = ws;
    ws += (bytes + 255) & ~(size_t)255;
    return p;
  };
  __hip_bfloat16* xb  = (__hip_bfloat16*)alloc((size_t)SEQ * DMODEL * 2);
  __hip_bfloat16* wqb = (__hip_bfloat16*)alloc((size_t)QD * DMODEL * 2);
  __hip_bfloat16* wkb = (__hip_bfloat16*)alloc((size_t)KVD * DMODEL * 2);
  __hip_bfloat16* wvb = (__hip_bfloat16*)alloc((size_t)KVD * DMODEL * 2);
  __hip_bfloat16* wob = (__hip_bfloat16*)alloc((size_t)DMODEL * QD * 2);
  __hip_bfloat16* Qb  = (__hip_bfloat16*)alloc((size_t)SEQ * QD * 2);
  __hip_bfloat16* Kc  = (__hip_bfloat16*)alloc((size_t)SEQ * KVD * 2);
  __hip_bfloat16* Vtg = (__hip_bfloat16*)alloc((size_t)KVD * SEQ * 2);
  __hip_bfloat16* Ob  = (__hip_bfloat16*)alloc((size_t)SEQ * QD * 2);

  auto cvt = [&](const float* src, __hip_bfloat16* dst, size_t n) {
    int n8 = (int)(n / 8);
    k_cvt<<<dim3((n8 + 255) / 256), dim3(256), 0, stream>>>(src, dst, n8);
  };
  cvt(x,  xb,  (size_t)SEQ * DMODEL);
  cvt(wq, wqb, (size_t)QD * DMODEL);
  cvt(wk, wkb, (size_t)KVD * DMODEL);
  cvt(wv, wvb, (size_t)KVD * DMODEL);
  cvt(wo, wob, (size_t)DMODEL * QD);

  k_gemm_bt<__hip_bfloat16><<<dim3(QD / 128, SEQ / 128), 256, 0, stream>>>(xb, wqb, Qb, SEQ, QD, DMODEL);
  k_gemm_kv<<<dim3(16, SEQ / 128), 256, 0, stream>>>(xb, wkb, wvb, Kc, Vtg);

  k_rope<<<dim3(SEQ * NH * 64 / 256), 256, 0, stream>>>(Qb, fc, fs, NH);
  k_rope<<<dim3(SEQ * NKVH * 64 / 256), 256, 0, stream>>>(Kc, fc, fs, NKVH);

  k_flash<<<dim3(32, NH), 256, 0, stream>>>(Qb, Kc, Vtg, Ob);

  k_gemm_bt<float><<<dim3(DMODEL / 128, SEQ / 128), 256, 0, stream>>>(Ob, wob, out, SEQ, DMODEL, DMODEL);
}

// Round 5
// 342.365 us; speedup vs baseline: 2.1838x; 2.1838x over previous
//
#include <hip/hip_runtime.h>
#include <hip/hip_bf16.h>
#include <stdint.h>

#define SEQ    2048
#define DMODEL 4096
#define NH     32
#define NKVH   8
#define HDIM   128
#define KVD    (NKVH*HDIM)   // 1024
#define QD     (NH*HDIM)     // 4096
#define ASCALE 0.08838834764831845f

typedef __attribute__((ext_vector_type(8))) short s8v;   // 8 bf16
typedef __attribute__((ext_vector_type(4))) short s4v;   // 4 bf16
typedef __attribute__((ext_vector_type(4))) float f4v;   // 4 f32

#define MFMA16(acc, a, b) \
  asm("v_mfma_f32_16x16x32_bf16 %0, %1, %2, %0" : "+v"(acc) : "v"(a), "v"(b))

__device__ __forceinline__ void gl2lds16(const void* g, void* l) {
  __builtin_amdgcn_global_load_lds(
      (const __attribute__((address_space(1))) void*)g,
      (__attribute__((address_space(3))) void*)l, 16, 0, 0);
}

__device__ __forceinline__ void store_out(__hip_bfloat16* p, float v) { *p = __float2bfloat16(v); }
__device__ __forceinline__ void store_out(float* p, float v) { *p = v; }

// ---------------- f32 -> bf16 convert (with optional scale folded pre-round) ----------------
__global__ __launch_bounds__(256) void k_cvt(const float* __restrict__ in,
                                             __hip_bfloat16* __restrict__ out, int n8,
                                             float scale) {
  int i = blockIdx.x * 256 + threadIdx.x;
  if (i >= n8) return;
  const float4* p = (const float4*)in + (size_t)i * 2;
  float4 a = p[0], b = p[1];
  union { __hip_bfloat16 h[8]; s8v v; } o;
  o.h[0] = __float2bfloat16(a.x * scale); o.h[1] = __float2bfloat16(a.y * scale);
  o.h[2] = __float2bfloat16(a.z * scale); o.h[3] = __float2bfloat16(a.w * scale);
  o.h[4] = __float2bfloat16(b.x * scale); o.h[5] = __float2bfloat16(b.y * scale);
  o.h[6] = __float2bfloat16(b.z * scale); o.h[7] = __float2bfloat16(b.w * scale);
  *(s8v*)(out + (size_t)i * 8) = o.v;
}

// ---------------- RoPE in-place on bf16 ----------------
__global__ __launch_bounds__(256) void k_rope(__hip_bfloat16* __restrict__ t,
                                              const float* __restrict__ fc,
                                              const float* __restrict__ fs, int heads) {
  int pid = blockIdx.x * 256 + threadIdx.x;
  int i = pid & 63;
  int rest = pid >> 6;
  int h = rest % heads;
  int s = rest / heads;
  size_t base = ((size_t)s * heads + h) * HDIM + 2 * i;
  uint32_t u = *(const uint32_t*)(t + base);
  __hip_bfloat16 hh[2]; *(uint32_t*)hh = u;
  float tr = __bfloat162float(hh[0]), ti = __bfloat162float(hh[1]);
  float c = fc[(size_t)s * 64 + i], sv = fs[(size_t)s * 64 + i];
  hh[0] = __float2bfloat16(tr * c - ti * sv);
  hh[1] = __float2bfloat16(tr * sv + ti * c);
  *(uint32_t*)(t + base) = *(uint32_t*)hh;
}

// ---------------- C = A(M,K) * B(N,K)^T (m97 structure, verified R1/R3) ----------------
template <typename OT>
__global__ __launch_bounds__(256) void k_gemm_bt(const __hip_bfloat16* __restrict__ A,
                                                 const __hip_bfloat16* __restrict__ B,
                                                 OT* __restrict__ C, int M, int N, int K) {
  __shared__ __align__(16) __hip_bfloat16 As[128 * 64];
  __shared__ __align__(16) __hip_bfloat16 Bs[128 * 64];
  const int t = threadIdx.x;
  const int wave = t >> 6, lane = t & 63;
  const int lrow = lane & 15, kq = lane >> 4;
  const int wr = wave >> 1, wc = wave & 1;
  const int m0 = blockIdx.y * 128, n0 = blockIdx.x * 128;

  f4v acc[4][4] = {};

  for (int k0 = 0; k0 < K; k0 += 64) {
#pragma unroll
    for (int it = 0; it < 4; ++it) {
      int chunk = it * 256 + t;
      int r = chunk >> 3;
      int cc = ((chunk & 7) ^ (r & 7)) * 8;
      gl2lds16(A + (size_t)(m0 + r) * K + k0 + cc, (char*)As + it * 4096 + wave * 1024);
      gl2lds16(B + (size_t)(n0 + r) * K + k0 + cc, (char*)Bs + it * 4096 + wave * 1024);
    }
    __syncthreads();
#pragma unroll
    for (int kk = 0; kk < 64; kk += 32) {
      s8v af[4], bfr[4];
#pragma unroll
      for (int m = 0; m < 4; ++m) {
        int row = wr * 64 + m * 16 + lrow;
        af[m] = *(const s8v*)&As[row * 64 + ((kk + kq * 8) ^ ((row & 7) << 3))];
      }
#pragma unroll
      for (int n = 0; n < 4; ++n) {
        int row = wc * 64 + n * 16 + lrow;
        bfr[n] = *(const s8v*)&Bs[row * 64 + ((kk + kq * 8) ^ ((row & 7) << 3))];
      }
#pragma unroll
      for (int m = 0; m < 4; ++m)
#pragma unroll
        for (int n = 0; n < 4; ++n)
          MFMA16(acc[m][n], af[m], bfr[n]);
    }
    __syncthreads();
  }

#pragma unroll
  for (int m = 0; m < 4; ++m)
#pragma unroll
    for (int n = 0; n < 4; ++n)
#pragma unroll
      for (int j = 0; j < 4; ++j) {
        int r = m0 + wr * 64 + m * 16 + kq * 4 + j;
        int c = n0 + wc * 64 + n * 16 + lrow;
        store_out(&C[(size_t)r * N + c], acc[m][n][j]);
      }
}

// ---------------- fused K+V projection: K row-major, V transposed (d-major) ----------------
__global__ __launch_bounds__(256) void k_gemm_kv(const __hip_bfloat16* __restrict__ A,
                                                 const __hip_bfloat16* __restrict__ Bk,
                                                 const __hip_bfloat16* __restrict__ Bv,
                                                 __hip_bfloat16* __restrict__ Ck,
                                                 __hip_bfloat16* __restrict__ Vt) {
  __shared__ __align__(16) __hip_bfloat16 As[128 * 64];
  __shared__ __align__(16) __hip_bfloat16 Bs[128 * 64];
  const int t = threadIdx.x;
  const int wave = t >> 6, lane = t & 63;
  const int lrow = lane & 15, kq = lane >> 4;
  const int wr = wave >> 1, wc = wave & 1;
  const int m0 = blockIdx.y * 128;
  const bool isV = blockIdx.x >= 8;
  const int n0 = (blockIdx.x & 7) * 128;
  const __hip_bfloat16* B = isV ? Bv : Bk;

  f4v acc[4][4] = {};

  for (int k0 = 0; k0 < DMODEL; k0 += 64) {
#pragma unroll
    for (int it = 0; it < 4; ++it) {
      int chunk = it * 256 + t;
      int r = chunk >> 3;
      int cc = ((chunk & 7) ^ (r & 7)) * 8;
      gl2lds16(A + (size_t)(m0 + r) * DMODEL + k0 + cc, (char*)As + it * 4096 + wave * 1024);
      gl2lds16(B + (size_t)(n0 + r) * DMODEL + k0 + cc, (char*)Bs + it * 4096 + wave * 1024);
    }
    __syncthreads();
#pragma unroll
    for (int kk = 0; kk < 64; kk += 32) {
      s8v af[4], bfr[4];
#pragma unroll
      for (int m = 0; m < 4; ++m) {
        int row = wr * 64 + m * 16 + lrow;
        af[m] = *(const s8v*)&As[row * 64 + ((kk + kq * 8) ^ ((row & 7) << 3))];
      }
#pragma unroll
      for (int n = 0; n < 4; ++n) {
        int row = wc * 64 + n * 16 + lrow;
        bfr[n] = *(const s8v*)&Bs[row * 64 + ((kk + kq * 8) ^ ((row & 7) << 3))];
      }
#pragma unroll
      for (int m = 0; m < 4; ++m)
#pragma unroll
        for (int n = 0; n < 4; ++n)
          MFMA16(acc[m][n], af[m], bfr[n]);
    }
    __syncthreads();
  }

  if (isV) {
#pragma unroll
    for (int m = 0; m < 4; ++m)
#pragma unroll
      for (int n = 0; n < 4; ++n) {
        int c = n0 + wc * 64 + n * 16 + lrow;
        int r0 = m0 + wr * 64 + m * 16 + kq * 4;
        union { __hip_bfloat16 b[4]; s4v v; } u;
#pragma unroll
        for (int j = 0; j < 4; ++j) u.b[j] = __float2bfloat16(acc[m][n][j]);
        *(s4v*)&Vt[(size_t)c * SEQ + r0] = u.v;
      }
  } else {
#pragma unroll
    for (int m = 0; m < 4; ++m)
#pragma unroll
      for (int n = 0; n < 4; ++n)
#pragma unroll
        for (int j = 0; j < 4; ++j) {
          int r = m0 + wr * 64 + m * 16 + kq * 4 + j;
          int c = n0 + wc * 64 + n * 16 + lrow;
          Ck[(size_t)r * KVD + c] = __float2bfloat16(acc[m][n][j]);
        }
  }
}

// ---------------- causal flash attention (R3 structure + VALU/DS trims) ----------------
// 4 waves, one head, paired q-tiles (qp, 31-qp) -> 33 tile-units/block, grid (16,NH).
// K double-buffered; V pre-transposed in HBM, staged + 16 ones-rows so the PV MFMA's
// 9th column accumulates l = sum(P) in the matrix pipe (replaces bpermute sum-reduce).
// ASCALE pre-folded into wq. Masking applied only on diagonal tiles. Rescale elided
// when fsc==1 exactly.
__global__ __launch_bounds__(256, 2) void k_flash(const __hip_bfloat16* __restrict__ Q,
                                                  const __hip_bfloat16* __restrict__ Kb,
                                                  const __hip_bfloat16* __restrict__ Vtg,
                                                  __hip_bfloat16* __restrict__ O) {
  __shared__ __align__(16) __hip_bfloat16 Ks[2][64 * 128];
  __shared__ __align__(16) __hip_bfloat16 Vs[144 * 64];   // rows 128..143 = ones
  __shared__ __align__(16) __hip_bfloat16 Ps[4][16 * 64];
  const int qp = blockIdx.x, h = blockIdx.y, g = h >> 2;
  const int t = threadIdx.x, wave = t >> 6, lane = t & 63;
  const int lrow = lane & 15, kq = lane >> 4;
  const int qtA = qp, qtB = 31 - qp;

  s8v qfA[4], qfB[4];
  {
    const int qrA = qtA * 64 + wave * 16 + lrow;
    const int qrB = qtB * 64 + wave * 16 + lrow;
#pragma unroll
    for (int tt = 0; tt < 4; ++tt) {
      qfA[tt] = *(const s8v*)(Q + (size_t)qrA * QD + h * HDIM + tt * 32 + kq * 8);
      qfB[tt] = *(const s8v*)(Q + (size_t)qrB * QD + h * HDIM + tt * 32 + kq * 8);
    }
  }

  // ones rows for the l-column (written once; first loop barrier publishes them)
  if (t < 128) {
    union { __hip_bfloat16 h8[8]; s8v v; } one;
#pragma unroll
    for (int e = 0; e < 8; ++e) one.h8[e] = __float2bfloat16(1.0f);
    *(s8v*)&Vs[128 * 64 + t * 8] = one.v;
  }

  f4v oA[9] = {}, oB[9] = {};   // [8] = l accumulator
  float mA[4], mB[4];
#pragma unroll
  for (int j = 0; j < 4; ++j) { mA[j] = mB[j] = -1e30f; }

  auto stage_k = [&](int buf, int kv) {
#pragma unroll
    for (int it = 0; it < 4; ++it) {
      int chunk = it * 256 + t;
      int r = chunk >> 4, cc = ((chunk & 15) ^ (r & 7)) * 8;
      gl2lds16(Kb + (size_t)(kv * 64 + r) * KVD + g * HDIM + cc,
               (char*)&Ks[buf][0] + it * 4096 + wave * 1024);
    }
  };
  auto stage_v = [&](int kv) {
#pragma unroll
    for (int it = 0; it < 4; ++it) {
      int chunk = it * 256 + t;
      int d = chunk >> 3, cc = ((chunk & 7) ^ (d & 7)) * 8;
      gl2lds16(Vtg + (size_t)(g * HDIM + d) * SEQ + kv * 64 + cc,
               (char*)Vs + it * 4096 + wave * 1024);
    }
  };

  auto soft_pv = [&](f4v (&s)[4], int qt, int kv, f4v (&acc_o)[9], float (&mrun)[4]) {
    __hip_bfloat16* P = &Ps[wave][0];
    const bool diag = (kv == qt);
    asm volatile("" ::: "memory");
#pragma unroll
    for (int j = 0; j < 4; ++j) {
      float p4[4];
      float mx = -1e30f;
#pragma unroll
      for (int n = 0; n < 4; ++n) {
        float v = s[n][j];
        if (diag) {
          const int qi = qt * 64 + wave * 16 + kq * 4 + j;
          int ki = kv * 64 + n * 16 + lrow;
          if (ki > qi) v = -1e30f;
        }
        p4[n] = v;
        mx = fmaxf(mx, v);
      }
#pragma unroll
      for (int msk = 1; msk < 16; msk <<= 1) mx = fmaxf(mx, __shfl_xor(mx, msk, 64));
      if (!__all(mx <= mrun[j])) {   // else fsc==1 exactly -> elide (bit-exact)
        float mnew = fmaxf(mrun[j], mx);
        float fsc = __expf(mrun[j] - mnew);
        mrun[j] = mnew;
#pragma unroll
        for (int n = 0; n < 9; ++n) acc_o[n][j] *= fsc;
      }
      const int drow = kq * 4 + j;
#pragma unroll
      for (int n = 0; n < 4; ++n) {
        float p = __expf(p4[n] - mrun[j]);
        P[drow * 64 + ((n * 16 + lrow) ^ ((drow & 7) << 3))] = __float2bfloat16(p);
      }
    }
    asm volatile("" ::: "memory");
#pragma unroll
    for (int tt = 0; tt < 2; ++tt) {
      s8v pa = *(const s8v*)&P[lrow * 64 + ((tt * 32 + kq * 8) ^ ((lrow & 7) << 3))];
#pragma unroll
      for (int n = 0; n < 9; ++n) {          // n==8: ones rows -> l accumulation
        int d = n * 16 + lrow;
        s8v vf = *(const s8v*)&Vs[d * 64 + ((tt * 32 + kq * 8) ^ ((d & 7) << 3))];
        MFMA16(acc_o[n], pa, vf);
      }
    }
  };

  stage_k(0, 0);
  int cur = 0;
  for (int kv = 0; kv <= qtB; ++kv) {
    const bool actA = (kv <= qtA);
    __syncthreads();                  // K[cur] staged; prior-iter Vs/Ps reads done
    if (kv < qtB) stage_k(cur ^ 1, kv + 1);
    stage_v(kv);

    f4v sB[4] = {}, sA[4] = {};
    if (actA) {
#pragma unroll
      for (int tt = 0; tt < 4; ++tt)
#pragma unroll
        for (int n = 0; n < 4; ++n) {
          int row = n * 16 + lrow;
          s8v kf = *(const s8v*)&Ks[cur][row * 128 + ((tt * 32 + kq * 8) ^ ((row & 7) << 3))];
          MFMA16(sB[n], qfB[tt], kf);
          MFMA16(sA[n], qfA[tt], kf);
        }
    } else {
#pragma unroll
      for (int tt = 0; tt < 4; ++tt)
#pragma unroll
        for (int n = 0; n < 4; ++n) {
          int row = n * 16 + lrow;
          s8v kf = *(const s8v*)&Ks[cur][row * 128 + ((tt * 32 + kq * 8) ^ ((row & 7) << 3))];
          MFMA16(sB[n], qfB[tt], kf);
        }
    }
    __syncthreads();                  // Vs(kv) staged (vmcnt drained)

    soft_pv(sB, qtB, kv, oB, mB);
    if (actA) soft_pv(sA, qtA, kv, oA, mA);
    cur ^= 1;
  }

#pragma unroll
  for (int n = 0; n < 8; ++n)
#pragma unroll
    for (int j = 0; j < 4; ++j) {
      int d = n * 16 + lrow;
      int qiB = qtB * 64 + wave * 16 + kq * 4 + j;
      O[(size_t)qiB * QD + h * HDIM + d] = __float2bfloat16(oB[n][j] / oB[8][j]);
      int qiA = qtA * 64 + wave * 16 + kq * 4 + j;
      O[(size_t)qiA * QD + h * HDIM + d] = __float2bfloat16(oA[n][j] / oA[8][j]);
    }
}

// ---------------- launch ----------------
extern "C" void kernel_launch(void* const* d_in, const int* in_sizes, int n_in,
                              void* d_out, int out_size, void* d_ws, size_t ws_size,
                              hipStream_t stream) {
  const float* x  = (const float*)d_in[0];
  const float* fc = (const float*)d_in[1];
  const float* fs = (const float*)d_in[2];
  const float* wq = (const float*)d_in[3];
  const float* wk = (const float*)d_in[4];
  const float* wv = (const float*)d_in[5];
  const float* wo = (const float*)d_in[6];
  float* out = (float*)d_out;

  char* ws = (char*)d_ws;
  auto alloc = [&](size_t bytes) {
    char* p = ws;
    ws += (bytes + 255) & ~(size_t)255;
    return p;
  };
  __hip_bfloat16* xb  = (__hip_bfloat16*)alloc((size_t)SEQ * DMODEL * 2);
  __hip_bfloat16* wqb = (__hip_bfloat16*)alloc((size_t)QD * DMODEL * 2);
  __hip_bfloat16* wkb = (__hip_bfloat16*)alloc((size_t)KVD * DMODEL * 2);
  __hip_bfloat16* wvb = (__hip_bfloat16*)alloc((size_t)KVD * DMODEL * 2);
  __hip_bfloat16* wob = (__hip_bfloat16*)alloc((size_t)DMODEL * QD * 2);
  __hip_bfloat16* Qb  = (__hip_bfloat16*)alloc((size_t)SEQ * QD * 2);
  __hip_bfloat16* Kc  = (__hip_bfloat16*)alloc((size_t)SEQ * KVD * 2);
  __hip_bfloat16* Vtg = (__hip_bfloat16*)alloc((size_t)KVD * SEQ * 2);
  __hip_bfloat16* Ob  = (__hip_bfloat16*)alloc((size_t)SEQ * QD * 2);

  auto cvt = [&](const float* src, __hip_bfloat16* dst, size_t n, float scale) {
    int n8 = (int)(n / 8);
    k_cvt<<<dim3((n8 + 255) / 256), dim3(256), 0, stream>>>(src, dst, n8, scale);
  };
  cvt(x,  xb,  (size_t)SEQ * DMODEL, 1.0f);
  cvt(wq, wqb, (size_t)QD * DMODEL, ASCALE);   // fold softmax scale into Q projection
  cvt(wk, wkb, (size_t)KVD * DMODEL, 1.0f);
  cvt(wv, wvb, (size_t)KVD * DMODEL, 1.0f);
  cvt(wo, wob, (size_t)DMODEL * QD, 1.0f);

  k_gemm_bt<__hip_bfloat16><<<dim3(QD / 128, SEQ / 128), 256, 0, stream>>>(xb, wqb, Qb, SEQ, QD, DMODEL);
  k_gemm_kv<<<dim3(16, SEQ / 128), 256, 0, stream>>>(xb, wkb, wvb, Kc, Vtg);

  k_rope<<<dim3(SEQ * NH * 64 / 256), 256, 0, stream>>>(Qb, fc, fs, NH);
  k_rope<<<dim3(SEQ * NKVH * 64 / 256), 256, 0, stream>>>(Kc, fc, fs, NKVH);

  k_flash<<<dim3(16, NH), 256, 0, stream>>>(Qb, Kc, Vtg, Ob);

  k_gemm_bt<float><<<dim3(DMODEL / 128, SEQ / 128), 256, 0, stream>>>(Ob, wob, out, SEQ, DMODEL, DMODEL);
}

// Round 6
// 300.126 us; speedup vs baseline: 2.4912x; 1.1407x over previous
//
#include <hip/hip_runtime.h>
#include <hip/hip_bf16.h>
#include <stdint.h>

#define SEQ    2048
#define DMODEL 4096
#define NH     32
#define NKVH   8
#define HDIM   128
#define KVD    (NKVH*HDIM)   // 1024
#define QD     (NH*HDIM)     // 4096
#define QKVN   (QD + 2*KVD)  // 6144 fused projection columns
#define ASCALE 0.08838834764831845f

typedef __attribute__((ext_vector_type(8))) short s8v;   // 8 bf16
typedef __attribute__((ext_vector_type(4))) short s4v;   // 4 bf16
typedef __attribute__((ext_vector_type(4))) float f4v;   // 4 f32

#define MFMA16(acc, a, b) \
  asm("v_mfma_f32_16x16x32_bf16 %0, %1, %2, %0" : "+v"(acc) : "v"(a), "v"(b))

// sched_barrier(0) + raw s_barrier + sched_barrier(0): phase fence without the
// __syncthreads() vmcnt(0)-drain (the m97 ~20% stall).
#define SBAR() do { __builtin_amdgcn_sched_barrier(0); \
                    __builtin_amdgcn_s_barrier();      \
                    __builtin_amdgcn_sched_barrier(0); } while (0)

__device__ __forceinline__ void gl2lds16(const void* g, void* l) {
  __builtin_amdgcn_global_load_lds(
      (const __attribute__((address_space(1))) void*)g,
      (__attribute__((address_space(3))) void*)l, 16, 0, 0);
}

__device__ __forceinline__ void store_out(__hip_bfloat16* p, float v) { *p = __float2bfloat16(v); }
__device__ __forceinline__ void store_out(float* p, float v) { *p = v; }

// ---------------- f32 -> bf16 convert (scale folded pre-round) ----------------
__global__ __launch_bounds__(256) void k_cvt(const float* __restrict__ in,
                                             __hip_bfloat16* __restrict__ out, int n8,
                                             float scale) {
  int i = blockIdx.x * 256 + threadIdx.x;
  if (i >= n8) return;
  const float4* p = (const float4*)in + (size_t)i * 2;
  float4 a = p[0], b = p[1];
  union { __hip_bfloat16 h[8]; s8v v; } o;
  o.h[0] = __float2bfloat16(a.x * scale); o.h[1] = __float2bfloat16(a.y * scale);
  o.h[2] = __float2bfloat16(a.z * scale); o.h[3] = __float2bfloat16(a.w * scale);
  o.h[4] = __float2bfloat16(b.x * scale); o.h[5] = __float2bfloat16(b.y * scale);
  o.h[6] = __float2bfloat16(b.z * scale); o.h[7] = __float2bfloat16(b.w * scale);
  *(s8v*)(out + (size_t)i * 8) = o.v;
}

// ---------------- RoPE in-place on bf16 ----------------
__global__ __launch_bounds__(256) void k_rope(__hip_bfloat16* __restrict__ t,
                                              const float* __restrict__ fc,
                                              const float* __restrict__ fs, int heads) {
  int pid = blockIdx.x * 256 + threadIdx.x;
  int i = pid & 63;
  int rest = pid >> 6;
  int h = rest % heads;
  int s = rest / heads;
  size_t base = ((size_t)s * heads + h) * HDIM + 2 * i;
  uint32_t u = *(const uint32_t*)(t + base);
  __hip_bfloat16 hh[2]; *(uint32_t*)hh = u;
  float tr = __bfloat162float(hh[0]), ti = __bfloat162float(hh[1]);
  float c = fc[(size_t)s * 64 + i], sv = fs[(size_t)s * 64 + i];
  hh[0] = __float2bfloat16(tr * c - ti * sv);
  hh[1] = __float2bfloat16(tr * sv + ti * c);
  *(uint32_t*)(t + base) = *(uint32_t*)hh;
}

// ---------------- fused QKV projection: 8-phase counted-vmcnt 256x192 tile ----------------
// 512 thr = 8 waves (2M x 4N), per-wave 128x48 output (8x3 16x16 frags), BK=64.
// LDS 112KB: 2 bufs x (A 256x64 + B 192x64). Per K-tile (4 phases):
//   ph1: ds_read k0 frags (11 b128) + MFMA k0,m0-3   ph2: ds_read k1 + MFMA k0,m4-7
//   ph3: stage A(t+2) + MFMA k1,m0-3                 ph4: stage B(t+2) + MFMA k1,m4-7
// Race-safety: tile t's LDS reads complete by end-ph2 (barrier); stages of t+2
// (same parity slots) issue only ph3/ph4. Boundary: vmcnt(7) keeps next tile's 7
// staging loads in flight (counted, never 0 mid-loop) + raw s_barrier.
__global__ __launch_bounds__(512, 2) void k_qkv(const __hip_bfloat16* __restrict__ A,
                                                const __hip_bfloat16* __restrict__ W,
                                                __hip_bfloat16* __restrict__ Qb,
                                                __hip_bfloat16* __restrict__ Kc,
                                                __hip_bfloat16* __restrict__ Vt) {
  __shared__ __align__(16) __hip_bfloat16 sm[2][256 * 64 + 192 * 64];
  const int t5 = threadIdx.x;
  const int wave = t5 >> 6, lane = t5 & 63;
  const int lrow = lane & 15, kq = lane >> 4;
  const int wm = wave >> 2, wn = wave & 3;
  const int mt = blockIdx.x & 7, nt = blockIdx.x >> 3;  // XCD-swizzle: XCD owns one A-panel
  const int m0 = mt * 256, n0 = nt * 192;

  auto stageA = [&](int p, int kt) {
#pragma unroll
    for (int it = 0; it < 4; ++it) {
      int chunk = it * 512 + t5;
      int r = chunk >> 3, cc = ((chunk & 7) ^ (r & 7)) * 8;
      gl2lds16(A + (size_t)(m0 + r) * DMODEL + kt * 64 + cc,
               (char*)&sm[p][0] + it * 8192 + wave * 1024);
    }
  };
  auto stageB = [&](int p, int kt) {
#pragma unroll
    for (int it = 0; it < 3; ++it) {
      int chunk = it * 512 + t5;
      int r = chunk >> 3, cc = ((chunk & 7) ^ (r & 7)) * 8;
      gl2lds16(W + (size_t)(n0 + r) * DMODEL + kt * 64 + cc,
               (char*)&sm[p][0] + 32768 + it * 8192 + wave * 1024);
    }
  };

  f4v acc[8][3] = {};

  // prologue: tiles 0 and 1 in flight (14 loads)
  stageA(0, 0); stageB(0, 0);
  stageA(1, 1); stageB(1, 1);

  const int NT = DMODEL / 64;
#pragma unroll 2
  for (int t = 0; t < NT; ++t) {
    const int p = t & 1;
    const __hip_bfloat16* As = &sm[p][0];
    const __hip_bfloat16* Bs = &sm[p][256 * 64];

    // tile boundary: tile t's stages landed; tile t+1's (7 loads) stay in flight
    __builtin_amdgcn_sched_barrier(0);
    if (t == NT - 1) asm volatile("s_waitcnt vmcnt(0)" ::: "memory");
    else             asm volatile("s_waitcnt vmcnt(7)" ::: "memory");
    __builtin_amdgcn_s_barrier();
    __builtin_amdgcn_sched_barrier(0);

    // ph1: read k0 fragments, MFMA k0 x m0-3
    s8v a0[8], b0[3];
#pragma unroll
    for (int m = 0; m < 8; ++m) {
      int row = wm * 128 + m * 16 + lrow;
      a0[m] = *(const s8v*)&As[row * 64 + ((kq * 8) ^ ((row & 7) << 3))];
    }
#pragma unroll
    for (int n = 0; n < 3; ++n) {
      int row = wn * 48 + n * 16 + lrow;
      b0[n] = *(const s8v*)&Bs[row * 64 + ((kq * 8) ^ ((row & 7) << 3))];
    }
    __builtin_amdgcn_s_setprio(1);
#pragma unroll
    for (int m = 0; m < 4; ++m)
#pragma unroll
      for (int n = 0; n < 3; ++n) MFMA16(acc[m][n], a0[m], b0[n]);
    __builtin_amdgcn_s_setprio(0);
    SBAR();

    // ph2: read k1 fragments, MFMA k0 x m4-7
    s8v a1[8], b1[3];
#pragma unroll
    for (int m = 0; m < 8; ++m) {
      int row = wm * 128 + m * 16 + lrow;
      a1[m] = *(const s8v*)&As[row * 64 + ((32 + kq * 8) ^ ((row & 7) << 3))];
    }
#pragma unroll
    for (int n = 0; n < 3; ++n) {
      int row = wn * 48 + n * 16 + lrow;
      b1[n] = *(const s8v*)&Bs[row * 64 + ((32 + kq * 8) ^ ((row & 7) << 3))];
    }
    __builtin_amdgcn_s_setprio(1);
#pragma unroll
    for (int m = 4; m < 8; ++m)
#pragma unroll
      for (int n = 0; n < 3; ++n) MFMA16(acc[m][n], a0[m], b0[n]);
    __builtin_amdgcn_s_setprio(0);
    SBAR();   // all waves' reads of buf p complete -> safe to overwrite

    // ph3: stage A of tile t+2 (same parity slots), MFMA k1 x m0-3
    if (t + 2 < NT) stageA(p, t + 2);
    __builtin_amdgcn_s_setprio(1);
#pragma unroll
    for (int m = 0; m < 4; ++m)
#pragma unroll
      for (int n = 0; n < 3; ++n) MFMA16(acc[m][n], a1[m], b1[n]);
    __builtin_amdgcn_s_setprio(0);
    SBAR();

    // ph4: stage B of tile t+2, MFMA k1 x m4-7
    if (t + 2 < NT) stageB(p, t + 2);
    __builtin_amdgcn_s_setprio(1);
#pragma unroll
    for (int m = 4; m < 8; ++m)
#pragma unroll
      for (int n = 0; n < 3; ++n) MFMA16(acc[m][n], a1[m], b1[n]);
    __builtin_amdgcn_s_setprio(0);
    // loop-top boundary supplies the next barrier
  }

  // epilogue: route columns to Q (row-major), K (row-major), V (transposed)
#pragma unroll
  for (int m = 0; m < 8; ++m)
#pragma unroll
    for (int n = 0; n < 3; ++n) {
      int c = n0 + wn * 48 + n * 16 + lrow;
      int r0 = m0 + wm * 128 + m * 16 + kq * 4;
      if (c < QD) {
#pragma unroll
        for (int j = 0; j < 4; ++j)
          Qb[(size_t)(r0 + j) * QD + c] = __float2bfloat16(acc[m][n][j]);
      } else if (c < QD + KVD) {
#pragma unroll
        for (int j = 0; j < 4; ++j)
          Kc[(size_t)(r0 + j) * KVD + (c - QD)] = __float2bfloat16(acc[m][n][j]);
      } else {
        union { __hip_bfloat16 b[4]; s4v v; } u;
#pragma unroll
        for (int j = 0; j < 4; ++j) u.b[j] = __float2bfloat16(acc[m][n][j]);
        *(s4v*)&Vt[(size_t)(c - QD - KVD) * SEQ + r0] = u.v;
      }
    }
}

// ---------------- C = A(M,K) * B(N,K)^T (m97 structure, verified) — O-proj ----------------
template <typename OT>
__global__ __launch_bounds__(256) void k_gemm_bt(const __hip_bfloat16* __restrict__ A,
                                                 const __hip_bfloat16* __restrict__ B,
                                                 OT* __restrict__ C, int M, int N, int K) {
  __shared__ __align__(16) __hip_bfloat16 As[128 * 64];
  __shared__ __align__(16) __hip_bfloat16 Bs[128 * 64];
  const int t = threadIdx.x;
  const int wave = t >> 6, lane = t & 63;
  const int lrow = lane & 15, kq = lane >> 4;
  const int wr = wave >> 1, wc = wave & 1;
  const int m0 = blockIdx.y * 128, n0 = blockIdx.x * 128;

  f4v acc[4][4] = {};

  for (int k0 = 0; k0 < K; k0 += 64) {
#pragma unroll
    for (int it = 0; it < 4; ++it) {
      int chunk = it * 256 + t;
      int r = chunk >> 3;
      int cc = ((chunk & 7) ^ (r & 7)) * 8;
      gl2lds16(A + (size_t)(m0 + r) * K + k0 + cc, (char*)As + it * 4096 + wave * 1024);
      gl2lds16(B + (size_t)(n0 + r) * K + k0 + cc, (char*)Bs + it * 4096 + wave * 1024);
    }
    __syncthreads();
#pragma unroll
    for (int kk = 0; kk < 64; kk += 32) {
      s8v af[4], bfr[4];
#pragma unroll
      for (int m = 0; m < 4; ++m) {
        int row = wr * 64 + m * 16 + lrow;
        af[m] = *(const s8v*)&As[row * 64 + ((kk + kq * 8) ^ ((row & 7) << 3))];
      }
#pragma unroll
      for (int n = 0; n < 4; ++n) {
        int row = wc * 64 + n * 16 + lrow;
        bfr[n] = *(const s8v*)&Bs[row * 64 + ((kk + kq * 8) ^ ((row & 7) << 3))];
      }
#pragma unroll
      for (int m = 0; m < 4; ++m)
#pragma unroll
        for (int n = 0; n < 4; ++n)
          MFMA16(acc[m][n], af[m], bfr[n]);
    }
    __syncthreads();
  }

#pragma unroll
  for (int m = 0; m < 4; ++m)
#pragma unroll
    for (int n = 0; n < 4; ++n)
#pragma unroll
      for (int j = 0; j < 4; ++j) {
        int r = m0 + wr * 64 + m * 16 + kq * 4 + j;
        int c = n0 + wc * 64 + n * 16 + lrow;
        store_out(&C[(size_t)r * N + c], acc[m][n][j]);
      }
}

// ---------------- causal flash attention (R5, unchanged) ----------------
__global__ __launch_bounds__(256, 2) void k_flash(const __hip_bfloat16* __restrict__ Q,
                                                  const __hip_bfloat16* __restrict__ Kb,
                                                  const __hip_bfloat16* __restrict__ Vtg,
                                                  __hip_bfloat16* __restrict__ O) {
  __shared__ __align__(16) __hip_bfloat16 Ks[2][64 * 128];
  __shared__ __align__(16) __hip_bfloat16 Vs[144 * 64];   // rows 128..143 = ones
  __shared__ __align__(16) __hip_bfloat16 Ps[4][16 * 64];
  const int qp = blockIdx.x, h = blockIdx.y, g = h >> 2;
  const int t = threadIdx.x, wave = t >> 6, lane = t & 63;
  const int lrow = lane & 15, kq = lane >> 4;
  const int qtA = qp, qtB = 31 - qp;

  s8v qfA[4], qfB[4];
  {
    const int qrA = qtA * 64 + wave * 16 + lrow;
    const int qrB = qtB * 64 + wave * 16 + lrow;
#pragma unroll
    for (int tt = 0; tt < 4; ++tt) {
      qfA[tt] = *(const s8v*)(Q + (size_t)qrA * QD + h * HDIM + tt * 32 + kq * 8);
      qfB[tt] = *(const s8v*)(Q + (size_t)qrB * QD + h * HDIM + tt * 32 + kq * 8);
    }
  }

  if (t < 128) {
    union { __hip_bfloat16 h8[8]; s8v v; } one;
#pragma unroll
    for (int e = 0; e < 8; ++e) one.h8[e] = __float2bfloat16(1.0f);
    *(s8v*)&Vs[128 * 64 + t * 8] = one.v;
  }

  f4v oA[9] = {}, oB[9] = {};   // [8] = l accumulator
  float mA[4], mB[4];
#pragma unroll
  for (int j = 0; j < 4; ++j) { mA[j] = mB[j] = -1e30f; }

  auto stage_k = [&](int buf, int kv) {
#pragma unroll
    for (int it = 0; it < 4; ++it) {
      int chunk = it * 256 + t;
      int r = chunk >> 4, cc = ((chunk & 15) ^ (r & 7)) * 8;
      gl2lds16(Kb + (size_t)(kv * 64 + r) * KVD + g * HDIM + cc,
               (char*)&Ks[buf][0] + it * 4096 + wave * 1024);
    }
  };
  auto stage_v = [&](int kv) {
#pragma unroll
    for (int it = 0; it < 4; ++it) {
      int chunk = it * 256 + t;
      int d = chunk >> 3, cc = ((chunk & 7) ^ (d & 7)) * 8;
      gl2lds16(Vtg + (size_t)(g * HDIM + d) * SEQ + kv * 64 + cc,
               (char*)Vs + it * 4096 + wave * 1024);
    }
  };

  auto soft_pv = [&](f4v (&s)[4], int qt, int kv, f4v (&acc_o)[9], float (&mrun)[4]) {
    __hip_bfloat16* P = &Ps[wave][0];
    const bool diag = (kv == qt);
    asm volatile("" ::: "memory");
#pragma unroll
    for (int j = 0; j < 4; ++j) {
      float p4[4];
      float mx = -1e30f;
#pragma unroll
      for (int n = 0; n < 4; ++n) {
        float v = s[n][j];
        if (diag) {
          const int qi = qt * 64 + wave * 16 + kq * 4 + j;
          int ki = kv * 64 + n * 16 + lrow;
          if (ki > qi) v = -1e30f;
        }
        p4[n] = v;
        mx = fmaxf(mx, v);
      }
#pragma unroll
      for (int msk = 1; msk < 16; msk <<= 1) mx = fmaxf(mx, __shfl_xor(mx, msk, 64));
      if (!__all(mx <= mrun[j])) {
        float mnew = fmaxf(mrun[j], mx);
        float fsc = __expf(mrun[j] - mnew);
        mrun[j] = mnew;
#pragma unroll
        for (int n = 0; n < 9; ++n) acc_o[n][j] *= fsc;
      }
      const int drow = kq * 4 + j;
#pragma unroll
      for (int n = 0; n < 4; ++n) {
        float p = __expf(p4[n] - mrun[j]);
        P[drow * 64 + ((n * 16 + lrow) ^ ((drow & 7) << 3))] = __float2bfloat16(p);
      }
    }
    asm volatile("" ::: "memory");
#pragma unroll
    for (int tt = 0; tt < 2; ++tt) {
      s8v pa = *(const s8v*)&P[lrow * 64 + ((tt * 32 + kq * 8) ^ ((lrow & 7) << 3))];
#pragma unroll
      for (int n = 0; n < 9; ++n) {
        int d = n * 16 + lrow;
        s8v vf = *(const s8v*)&Vs[d * 64 + ((tt * 32 + kq * 8) ^ ((d & 7) << 3))];
        MFMA16(acc_o[n], pa, vf);
      }
    }
  };

  stage_k(0, 0);
  int cur = 0;
  for (int kv = 0; kv <= qtB; ++kv) {
    const bool actA = (kv <= qtA);
    __syncthreads();
    if (kv < qtB) stage_k(cur ^ 1, kv + 1);
    stage_v(kv);

    f4v sB[4] = {}, sA[4] = {};
    if (actA) {
#pragma unroll
      for (int tt = 0; tt < 4; ++tt)
#pragma unroll
        for (int n = 0; n < 4; ++n) {
          int row = n * 16 + lrow;
          s8v kf = *(const s8v*)&Ks[cur][row * 128 + ((tt * 32 + kq * 8) ^ ((row & 7) << 3))];
          MFMA16(sB[n], qfB[tt], kf);
          MFMA16(sA[n], qfA[tt], kf);
        }
    } else {
#pragma unroll
      for (int tt = 0; tt < 4; ++tt)
#pragma unroll
        for (int n = 0; n < 4; ++n) {
          int row = n * 16 + lrow;
          s8v kf = *(const s8v*)&Ks[cur][row * 128 + ((tt * 32 + kq * 8) ^ ((row & 7) << 3))];
          MFMA16(sB[n], qfB[tt], kf);
        }
    }
    __syncthreads();

    soft_pv(sB, qtB, kv, oB, mB);
    if (actA) soft_pv(sA, qtA, kv, oA, mA);
    cur ^= 1;
  }

#pragma unroll
  for (int n = 0; n < 8; ++n)
#pragma unroll
    for (int j = 0; j < 4; ++j) {
      int d = n * 16 + lrow;
      int qiB = qtB * 64 + wave * 16 + kq * 4 + j;
      O[(size_t)qiB * QD + h * HDIM + d] = __float2bfloat16(oB[n][j] / oB[8][j]);
      int qiA = qtA * 64 + wave * 16 + kq * 4 + j;
      O[(size_t)qiA * QD + h * HDIM + d] = __float2bfloat16(oA[n][j] / oA[8][j]);
    }
}

// ---------------- launch ----------------
extern "C" void kernel_launch(void* const* d_in, const int* in_sizes, int n_in,
                              void* d_out, int out_size, void* d_ws, size_t ws_size,
                              hipStream_t stream) {
  const float* x  = (const float*)d_in[0];
  const float* fc = (const float*)d_in[1];
  const float* fs = (const float*)d_in[2];
  const float* wq = (const float*)d_in[3];
  const float* wk = (const float*)d_in[4];
  const float* wv = (const float*)d_in[5];
  const float* wo = (const float*)d_in[6];
  float* out = (float*)d_out;

  char* ws = (char*)d_ws;
  auto alloc = [&](size_t bytes) {
    char* p = ws;
    ws += (bytes + 255) & ~(size_t)255;
    return p;
  };
  __hip_bfloat16* xb  = (__hip_bfloat16*)alloc((size_t)SEQ * DMODEL * 2);
  __hip_bfloat16* wf  = (__hip_bfloat16*)alloc((size_t)QKVN * DMODEL * 2);  // fused [wq;wk;wv]
  __hip_bfloat16* wob = (__hip_bfloat16*)alloc((size_t)DMODEL * QD * 2);
  __hip_bfloat16* Qb  = (__hip_bfloat16*)alloc((size_t)SEQ * QD * 2);
  __hip_bfloat16* Kc  = (__hip_bfloat16*)alloc((size_t)SEQ * KVD * 2);
  __hip_bfloat16* Vtg = (__hip_bfloat16*)alloc((size_t)KVD * SEQ * 2);
  __hip_bfloat16* Ob  = (__hip_bfloat16*)alloc((size_t)SEQ * QD * 2);

  auto cvt = [&](const float* src, __hip_bfloat16* dst, size_t n, float scale) {
    int n8 = (int)(n / 8);
    k_cvt<<<dim3((n8 + 255) / 256), dim3(256), 0, stream>>>(src, dst, n8, scale);
  };
  cvt(x,  xb, (size_t)SEQ * DMODEL, 1.0f);
  cvt(wq, wf, (size_t)QD * DMODEL, ASCALE);                              // rows 0..4095
  cvt(wk, wf + (size_t)QD * DMODEL, (size_t)KVD * DMODEL, 1.0f);         // rows 4096..5119
  cvt(wv, wf + (size_t)(QD + KVD) * DMODEL, (size_t)KVD * DMODEL, 1.0f); // rows 5120..6143
  cvt(wo, wob, (size_t)DMODEL * QD, 1.0f);

  k_qkv<<<dim3(256), dim3(512), 0, stream>>>(xb, wf, Qb, Kc, Vtg);

  k_rope<<<dim3(SEQ * NH * 64 / 256), 256, 0, stream>>>(Qb, fc, fs, NH);
  k_rope<<<dim3(SEQ * NKVH * 64 / 256), 256, 0, stream>>>(Kc, fc, fs, NKVH);

  k_flash<<<dim3(16, NH), 256, 0, stream>>>(Qb, Kc, Vtg, Ob);

  k_gemm_bt<float><<<dim3(DMODEL / 128, SEQ / 128), 256, 0, stream>>>(Ob, wob, out, SEQ, DMODEL, DMODEL);
}

// Round 7
// 294.861 us; speedup vs baseline: 2.5357x; 1.0179x over previous
//
#include <hip/hip_runtime.h>
#include <hip/hip_bf16.h>
#include <stdint.h>

#define SEQ    2048
#define DMODEL 4096
#define NH     32
#define NKVH   8
#define HDIM   128
#define KVD    (NKVH*HDIM)   // 1024
#define QD     (NH*HDIM)     // 4096
#define QKVN   (QD + 2*KVD)  // 6144 fused projection columns
#define ASCALE 0.08838834764831845f

typedef __attribute__((ext_vector_type(8))) short s8v;   // 8 bf16
typedef __attribute__((ext_vector_type(4))) short s4v;   // 4 bf16
typedef __attribute__((ext_vector_type(4))) float f4v;   // 4 f32

#define MFMA16(acc, a, b) \
  asm("v_mfma_f32_16x16x32_bf16 %0, %1, %2, %0" : "+v"(acc) : "v"(a), "v"(b))

#define SBAR() do { __builtin_amdgcn_sched_barrier(0); \
                    __builtin_amdgcn_s_barrier();      \
                    __builtin_amdgcn_sched_barrier(0); } while (0)

__device__ __forceinline__ void gl2lds16(const void* g, void* l) {
  __builtin_amdgcn_global_load_lds(
      (const __attribute__((address_space(1))) void*)g,
      (__attribute__((address_space(3))) void*)l, 16, 0, 0);
}

// ---------------- f32 -> bf16 convert (scale folded pre-round) ----------------
__global__ __launch_bounds__(256) void k_cvt(const float* __restrict__ in,
                                             __hip_bfloat16* __restrict__ out, int n8,
                                             float scale) {
  int i = blockIdx.x * 256 + threadIdx.x;
  if (i >= n8) return;
  const float4* p = (const float4*)in + (size_t)i * 2;
  float4 a = p[0], b = p[1];
  union { __hip_bfloat16 h[8]; s8v v; } o;
  o.h[0] = __float2bfloat16(a.x * scale); o.h[1] = __float2bfloat16(a.y * scale);
  o.h[2] = __float2bfloat16(a.z * scale); o.h[3] = __float2bfloat16(a.w * scale);
  o.h[4] = __float2bfloat16(b.x * scale); o.h[5] = __float2bfloat16(b.y * scale);
  o.h[6] = __float2bfloat16(b.z * scale); o.h[7] = __float2bfloat16(b.w * scale);
  *(s8v*)(out + (size_t)i * 8) = o.v;
}

// ---------------- RoPE in-place on bf16 ----------------
__global__ __launch_bounds__(256) void k_rope(__hip_bfloat16* __restrict__ t,
                                              const float* __restrict__ fc,
                                              const float* __restrict__ fs, int heads) {
  int pid = blockIdx.x * 256 + threadIdx.x;
  int i = pid & 63;
  int rest = pid >> 6;
  int h = rest % heads;
  int s = rest / heads;
  size_t base = ((size_t)s * heads + h) * HDIM + 2 * i;
  uint32_t u = *(const uint32_t*)(t + base);
  __hip_bfloat16 hh[2]; *(uint32_t*)hh = u;
  float tr = __bfloat162float(hh[0]), ti = __bfloat162float(hh[1]);
  float c = fc[(size_t)s * 64 + i], sv = fs[(size_t)s * 64 + i];
  hh[0] = __float2bfloat16(tr * c - ti * sv);
  hh[1] = __float2bfloat16(tr * sv + ti * c);
  *(uint32_t*)(t + base) = *(uint32_t*)hh;
}

// ---------------- fused QKV projection: 4-phase counted-vmcnt 256x192 (R6, verified) ----------------
__global__ __launch_bounds__(512, 2) void k_qkv(const __hip_bfloat16* __restrict__ A,
                                                const __hip_bfloat16* __restrict__ W,
                                                __hip_bfloat16* __restrict__ Qb,
                                                __hip_bfloat16* __restrict__ Kc,
                                                __hip_bfloat16* __restrict__ Vt) {
  __shared__ __align__(16) __hip_bfloat16 sm[2][256 * 64 + 192 * 64];
  const int t5 = threadIdx.x;
  const int wave = t5 >> 6, lane = t5 & 63;
  const int lrow = lane & 15, kq = lane >> 4;
  const int wm = wave >> 2, wn = wave & 3;
  const int mt = blockIdx.x & 7, nt = blockIdx.x >> 3;  // XCD-swizzle: XCD owns one A-panel
  const int m0 = mt * 256, n0 = nt * 192;

  auto stageA = [&](int p, int kt) {
#pragma unroll
    for (int it = 0; it < 4; ++it) {
      int chunk = it * 512 + t5;
      int r = chunk >> 3, cc = ((chunk & 7) ^ (r & 7)) * 8;
      gl2lds16(A + (size_t)(m0 + r) * DMODEL + kt * 64 + cc,
               (char*)&sm[p][0] + it * 8192 + wave * 1024);
    }
  };
  auto stageB = [&](int p, int kt) {
#pragma unroll
    for (int it = 0; it < 3; ++it) {
      int chunk = it * 512 + t5;
      int r = chunk >> 3, cc = ((chunk & 7) ^ (r & 7)) * 8;
      gl2lds16(W + (size_t)(n0 + r) * DMODEL + kt * 64 + cc,
               (char*)&sm[p][0] + 32768 + it * 8192 + wave * 1024);
    }
  };

  f4v acc[8][3] = {};

  stageA(0, 0); stageB(0, 0);
  stageA(1, 1); stageB(1, 1);

  const int NT = DMODEL / 64;
#pragma unroll 2
  for (int t = 0; t < NT; ++t) {
    const int p = t & 1;
    const __hip_bfloat16* As = &sm[p][0];
    const __hip_bfloat16* Bs = &sm[p][256 * 64];

    __builtin_amdgcn_sched_barrier(0);
    if (t == NT - 1) asm volatile("s_waitcnt vmcnt(0)" ::: "memory");
    else             asm volatile("s_waitcnt vmcnt(7)" ::: "memory");
    __builtin_amdgcn_s_barrier();
    __builtin_amdgcn_sched_barrier(0);

    s8v a0[8], b0[3];
#pragma unroll
    for (int m = 0; m < 8; ++m) {
      int row = wm * 128 + m * 16 + lrow;
      a0[m] = *(const s8v*)&As[row * 64 + ((kq * 8) ^ ((row & 7) << 3))];
    }
#pragma unroll
    for (int n = 0; n < 3; ++n) {
      int row = wn * 48 + n * 16 + lrow;
      b0[n] = *(const s8v*)&Bs[row * 64 + ((kq * 8) ^ ((row & 7) << 3))];
    }
    __builtin_amdgcn_s_setprio(1);
#pragma unroll
    for (int m = 0; m < 4; ++m)
#pragma unroll
      for (int n = 0; n < 3; ++n) MFMA16(acc[m][n], a0[m], b0[n]);
    __builtin_amdgcn_s_setprio(0);
    SBAR();

    s8v a1[8], b1[3];
#pragma unroll
    for (int m = 0; m < 8; ++m) {
      int row = wm * 128 + m * 16 + lrow;
      a1[m] = *(const s8v*)&As[row * 64 + ((32 + kq * 8) ^ ((row & 7) << 3))];
    }
#pragma unroll
    for (int n = 0; n < 3; ++n) {
      int row = wn * 48 + n * 16 + lrow;
      b1[n] = *(const s8v*)&Bs[row * 64 + ((32 + kq * 8) ^ ((row & 7) << 3))];
    }
    __builtin_amdgcn_s_setprio(1);
#pragma unroll
    for (int m = 4; m < 8; ++m)
#pragma unroll
      for (int n = 0; n < 3; ++n) MFMA16(acc[m][n], a0[m], b0[n]);
    __builtin_amdgcn_s_setprio(0);
    SBAR();

    if (t + 2 < NT) stageA(p, t + 2);
    __builtin_amdgcn_s_setprio(1);
#pragma unroll
    for (int m = 0; m < 4; ++m)
#pragma unroll
      for (int n = 0; n < 3; ++n) MFMA16(acc[m][n], a1[m], b1[n]);
    __builtin_amdgcn_s_setprio(0);
    SBAR();

    if (t + 2 < NT) stageB(p, t + 2);
    __builtin_amdgcn_s_setprio(1);
#pragma unroll
    for (int m = 4; m < 8; ++m)
#pragma unroll
      for (int n = 0; n < 3; ++n) MFMA16(acc[m][n], a1[m], b1[n]);
    __builtin_amdgcn_s_setprio(0);
  }

#pragma unroll
  for (int m = 0; m < 8; ++m)
#pragma unroll
    for (int n = 0; n < 3; ++n) {
      int c = n0 + wn * 48 + n * 16 + lrow;
      int r0 = m0 + wm * 128 + m * 16 + kq * 4;
      if (c < QD) {
#pragma unroll
        for (int j = 0; j < 4; ++j)
          Qb[(size_t)(r0 + j) * QD + c] = __float2bfloat16(acc[m][n][j]);
      } else if (c < QD + KVD) {
#pragma unroll
        for (int j = 0; j < 4; ++j)
          Kc[(size_t)(r0 + j) * KVD + (c - QD)] = __float2bfloat16(acc[m][n][j]);
      } else {
        union { __hip_bfloat16 b[4]; s4v v; } u;
#pragma unroll
        for (int j = 0; j < 4; ++j) u.b[j] = __float2bfloat16(acc[m][n][j]);
        *(s4v*)&Vt[(size_t)(c - QD - KVD) * SEQ + r0] = u.v;
      }
    }
}

// ---------------- O-projection: 4-phase counted-vmcnt 128x256 tile ----------------
// C(2048x4096 f32) = Ob(2048x4096) * wob(4096 rows x 4096 cols)^T.
// 512 thr = 8 waves (2M x 4N), per-wave 64x64 (4x4 frags), BK=64.
// LDS 96KB: 2 bufs x (A 128x64 + B 256x64). Grid 16x16 = 256 = exact CU fill.
// Same race-safe schedule as k_qkv: reads of buf p end at ph2 barrier; stages of
// tile t+2 (same parity) issue ph3/ph4; boundary vmcnt(6) (= t+1's 6 loads).
__global__ __launch_bounds__(512, 2) void k_oproj(const __hip_bfloat16* __restrict__ A,
                                                  const __hip_bfloat16* __restrict__ B,
                                                  float* __restrict__ C) {
  __shared__ __align__(16) __hip_bfloat16 sm[2][128 * 64 + 256 * 64];
  const int t5 = threadIdx.x;
  const int wave = t5 >> 6, lane = t5 & 63;
  const int lrow = lane & 15, kq = lane >> 4;
  const int wm = wave >> 2, wn = wave & 3;
  const int m0 = blockIdx.y * 128, n0 = blockIdx.x * 256;

  auto stageA = [&](int p, int kt) {
#pragma unroll
    for (int it = 0; it < 2; ++it) {
      int chunk = it * 512 + t5;
      int r = chunk >> 3, cc = ((chunk & 7) ^ (r & 7)) * 8;
      gl2lds16(A + (size_t)(m0 + r) * QD + kt * 64 + cc,
               (char*)&sm[p][0] + it * 8192 + wave * 1024);
    }
  };
  auto stageB = [&](int p, int kt) {
#pragma unroll
    for (int it = 0; it < 4; ++it) {
      int chunk = it * 512 + t5;
      int r = chunk >> 3, cc = ((chunk & 7) ^ (r & 7)) * 8;
      gl2lds16(B + (size_t)(n0 + r) * QD + kt * 64 + cc,
               (char*)&sm[p][0] + 16384 + it * 8192 + wave * 1024);
    }
  };

  f4v acc[4][4] = {};

  stageA(0, 0); stageB(0, 0);
  stageA(1, 1); stageB(1, 1);

  const int NT = QD / 64;
#pragma unroll 2
  for (int t = 0; t < NT; ++t) {
    const int p = t & 1;
    const __hip_bfloat16* As = &sm[p][0];
    const __hip_bfloat16* Bs = &sm[p][128 * 64];

    __builtin_amdgcn_sched_barrier(0);
    if (t == NT - 1) asm volatile("s_waitcnt vmcnt(0)" ::: "memory");
    else             asm volatile("s_waitcnt vmcnt(6)" ::: "memory");
    __builtin_amdgcn_s_barrier();
    __builtin_amdgcn_sched_barrier(0);

    // ph1: ds_read ks0 (8 b128), MFMA ks0 m0-1
    s8v a0[4], b0[4];
#pragma unroll
    for (int m = 0; m < 4; ++m) {
      int row = wm * 64 + m * 16 + lrow;
      a0[m] = *(const s8v*)&As[row * 64 + ((kq * 8) ^ ((row & 7) << 3))];
    }
#pragma unroll
    for (int n = 0; n < 4; ++n) {
      int row = wn * 64 + n * 16 + lrow;
      b0[n] = *(const s8v*)&Bs[row * 64 + ((kq * 8) ^ ((row & 7) << 3))];
    }
    __builtin_amdgcn_s_setprio(1);
#pragma unroll
    for (int m = 0; m < 2; ++m)
#pragma unroll
      for (int n = 0; n < 4; ++n) MFMA16(acc[m][n], a0[m], b0[n]);
    __builtin_amdgcn_s_setprio(0);
    SBAR();

    // ph2: ds_read ks1, MFMA ks0 m2-3
    s8v a1[4], b1[4];
#pragma unroll
    for (int m = 0; m < 4; ++m) {
      int row = wm * 64 + m * 16 + lrow;
      a1[m] = *(const s8v*)&As[row * 64 + ((32 + kq * 8) ^ ((row & 7) << 3))];
    }
#pragma unroll
    for (int n = 0; n < 4; ++n) {
      int row = wn * 64 + n * 16 + lrow;
      b1[n] = *(const s8v*)&Bs[row * 64 + ((32 + kq * 8) ^ ((row & 7) << 3))];
    }
    __builtin_amdgcn_s_setprio(1);
#pragma unroll
    for (int m = 2; m < 4; ++m)
#pragma unroll
      for (int n = 0; n < 4; ++n) MFMA16(acc[m][n], a0[m], b0[n]);
    __builtin_amdgcn_s_setprio(0);
    SBAR();   // all reads of buf p complete

    // ph3: stage A(t+2), MFMA ks1 m0-1
    if (t + 2 < NT) stageA(p, t + 2);
    __builtin_amdgcn_s_setprio(1);
#pragma unroll
    for (int m = 0; m < 2; ++m)
#pragma unroll
      for (int n = 0; n < 4; ++n) MFMA16(acc[m][n], a1[m], b1[n]);
    __builtin_amdgcn_s_setprio(0);
    SBAR();

    // ph4: stage B(t+2), MFMA ks1 m2-3
    if (t + 2 < NT) stageB(p, t + 2);
    __builtin_amdgcn_s_setprio(1);
#pragma unroll
    for (int m = 2; m < 4; ++m)
#pragma unroll
      for (int n = 0; n < 4; ++n) MFMA16(acc[m][n], a1[m], b1[n]);
    __builtin_amdgcn_s_setprio(0);
  }

#pragma unroll
  for (int m = 0; m < 4; ++m)
#pragma unroll
    for (int n = 0; n < 4; ++n)
#pragma unroll
      for (int j = 0; j < 4; ++j) {
        int r = m0 + wm * 64 + m * 16 + kq * 4 + j;
        int c = n0 + wn * 64 + n * 16 + lrow;
        C[(size_t)r * DMODEL + c] = acc[m][n][j];
      }
}

// ---------------- causal flash attention (R5, unchanged) ----------------
__global__ __launch_bounds__(256, 2) void k_flash(const __hip_bfloat16* __restrict__ Q,
                                                  const __hip_bfloat16* __restrict__ Kb,
                                                  const __hip_bfloat16* __restrict__ Vtg,
                                                  __hip_bfloat16* __restrict__ O) {
  __shared__ __align__(16) __hip_bfloat16 Ks[2][64 * 128];
  __shared__ __align__(16) __hip_bfloat16 Vs[144 * 64];   // rows 128..143 = ones
  __shared__ __align__(16) __hip_bfloat16 Ps[4][16 * 64];
  const int qp = blockIdx.x, h = blockIdx.y, g = h >> 2;
  const int t = threadIdx.x, wave = t >> 6, lane = t & 63;
  const int lrow = lane & 15, kq = lane >> 4;
  const int qtA = qp, qtB = 31 - qp;

  s8v qfA[4], qfB[4];
  {
    const int qrA = qtA * 64 + wave * 16 + lrow;
    const int qrB = qtB * 64 + wave * 16 + lrow;
#pragma unroll
    for (int tt = 0; tt < 4; ++tt) {
      qfA[tt] = *(const s8v*)(Q + (size_t)qrA * QD + h * HDIM + tt * 32 + kq * 8);
      qfB[tt] = *(const s8v*)(Q + (size_t)qrB * QD + h * HDIM + tt * 32 + kq * 8);
    }
  }

  if (t < 128) {
    union { __hip_bfloat16 h8[8]; s8v v; } one;
#pragma unroll
    for (int e = 0; e < 8; ++e) one.h8[e] = __float2bfloat16(1.0f);
    *(s8v*)&Vs[128 * 64 + t * 8] = one.v;
  }

  f4v oA[9] = {}, oB[9] = {};   // [8] = l accumulator
  float mA[4], mB[4];
#pragma unroll
  for (int j = 0; j < 4; ++j) { mA[j] = mB[j] = -1e30f; }

  auto stage_k = [&](int buf, int kv) {
#pragma unroll
    for (int it = 0; it < 4; ++it) {
      int chunk = it * 256 + t;
      int r = chunk >> 4, cc = ((chunk & 15) ^ (r & 7)) * 8;
      gl2lds16(Kb + (size_t)(kv * 64 + r) * KVD + g * HDIM + cc,
               (char*)&Ks[buf][0] + it * 4096 + wave * 1024);
    }
  };
  auto stage_v = [&](int kv) {
#pragma unroll
    for (int it = 0; it < 4; ++it) {
      int chunk = it * 256 + t;
      int d = chunk >> 3, cc = ((chunk & 7) ^ (d & 7)) * 8;
      gl2lds16(Vtg + (size_t)(g * HDIM + d) * SEQ + kv * 64 + cc,
               (char*)Vs + it * 4096 + wave * 1024);
    }
  };

  auto soft_pv = [&](f4v (&s)[4], int qt, int kv, f4v (&acc_o)[9], float (&mrun)[4]) {
    __hip_bfloat16* P = &Ps[wave][0];
    const bool diag = (kv == qt);
    asm volatile("" ::: "memory");
#pragma unroll
    for (int j = 0; j < 4; ++j) {
      float p4[4];
      float mx = -1e30f;
#pragma unroll
      for (int n = 0; n < 4; ++n) {
        float v = s[n][j];
        if (diag) {
          const int qi = qt * 64 + wave * 16 + kq * 4 + j;
          int ki = kv * 64 + n * 16 + lrow;
          if (ki > qi) v = -1e30f;
        }
        p4[n] = v;
        mx = fmaxf(mx, v);
      }
#pragma unroll
      for (int msk = 1; msk < 16; msk <<= 1) mx = fmaxf(mx, __shfl_xor(mx, msk, 64));
      if (!__all(mx <= mrun[j])) {
        float mnew = fmaxf(mrun[j], mx);
        float fsc = __expf(mrun[j] - mnew);
        mrun[j] = mnew;
#pragma unroll
        for (int n = 0; n < 9; ++n) acc_o[n][j] *= fsc;
      }
      const int drow = kq * 4 + j;
#pragma unroll
      for (int n = 0; n < 4; ++n) {
        float p = __expf(p4[n] - mrun[j]);
        P[drow * 64 + ((n * 16 + lrow) ^ ((drow & 7) << 3))] = __float2bfloat16(p);
      }
    }
    asm volatile("" ::: "memory");
#pragma unroll
    for (int tt = 0; tt < 2; ++tt) {
      s8v pa = *(const s8v*)&P[lrow * 64 + ((tt * 32 + kq * 8) ^ ((lrow & 7) << 3))];
#pragma unroll
      for (int n = 0; n < 9; ++n) {
        int d = n * 16 + lrow;
        s8v vf = *(const s8v*)&Vs[d * 64 + ((tt * 32 + kq * 8) ^ ((d & 7) << 3))];
        MFMA16(acc_o[n], pa, vf);
      }
    }
  };

  stage_k(0, 0);
  int cur = 0;
  for (int kv = 0; kv <= qtB; ++kv) {
    const bool actA = (kv <= qtA);
    __syncthreads();
    if (kv < qtB) stage_k(cur ^ 1, kv + 1);
    stage_v(kv);

    f4v sB[4] = {}, sA[4] = {};
    if (actA) {
#pragma unroll
      for (int tt = 0; tt < 4; ++tt)
#pragma unroll
        for (int n = 0; n < 4; ++n) {
          int row = n * 16 + lrow;
          s8v kf = *(const s8v*)&Ks[cur][row * 128 + ((tt * 32 + kq * 8) ^ ((row & 7) << 3))];
          MFMA16(sB[n], qfB[tt], kf);
          MFMA16(sA[n], qfA[tt], kf);
        }
    } else {
#pragma unroll
      for (int tt = 0; tt < 4; ++tt)
#pragma unroll
        for (int n = 0; n < 4; ++n) {
          int row = n * 16 + lrow;
          s8v kf = *(const s8v*)&Ks[cur][row * 128 + ((tt * 32 + kq * 8) ^ ((row & 7) << 3))];
          MFMA16(sB[n], qfB[tt], kf);
        }
    }
    __syncthreads();

    soft_pv(sB, qtB, kv, oB, mB);
    if (actA) soft_pv(sA, qtA, kv, oA, mA);
    cur ^= 1;
  }

#pragma unroll
  for (int n = 0; n < 8; ++n)
#pragma unroll
    for (int j = 0; j < 4; ++j) {
      int d = n * 16 + lrow;
      int qiB = qtB * 64 + wave * 16 + kq * 4 + j;
      O[(size_t)qiB * QD + h * HDIM + d] = __float2bfloat16(oB[n][j] / oB[8][j]);
      int qiA = qtA * 64 + wave * 16 + kq * 4 + j;
      O[(size_t)qiA * QD + h * HDIM + d] = __float2bfloat16(oA[n][j] / oA[8][j]);
    }
}

// ---------------- launch ----------------
extern "C" void kernel_launch(void* const* d_in, const int* in_sizes, int n_in,
                              void* d_out, int out_size, void* d_ws, size_t ws_size,
                              hipStream_t stream) {
  const float* x  = (const float*)d_in[0];
  const float* fc = (const float*)d_in[1];
  const float* fs = (const float*)d_in[2];
  const float* wq = (const float*)d_in[3];
  const float* wk = (const float*)d_in[4];
  const float* wv = (const float*)d_in[5];
  const float* wo = (const float*)d_in[6];
  float* out = (float*)d_out;

  char* ws = (char*)d_ws;
  auto alloc = [&](size_t bytes) {
    char* p = ws;
    ws += (bytes + 255) & ~(size_t)255;
    return p;
  };
  __hip_bfloat16* xb  = (__hip_bfloat16*)alloc((size_t)SEQ * DMODEL * 2);
  __hip_bfloat16* wf  = (__hip_bfloat16*)alloc((size_t)QKVN * DMODEL * 2);  // fused [wq;wk;wv]
  __hip_bfloat16* wob = (__hip_bfloat16*)alloc((size_t)DMODEL * QD * 2);
  __hip_bfloat16* Qb  = (__hip_bfloat16*)alloc((size_t)SEQ * QD * 2);
  __hip_bfloat16* Kc  = (__hip_bfloat16*)alloc((size_t)SEQ * KVD * 2);
  __hip_bfloat16* Vtg = (__hip_bfloat16*)alloc((size_t)KVD * SEQ * 2);
  __hip_bfloat16* Ob  = (__hip_bfloat16*)alloc((size_t)SEQ * QD * 2);

  auto cvt = [&](const float* src, __hip_bfloat16* dst, size_t n, float scale) {
    int n8 = (int)(n / 8);
    k_cvt<<<dim3((n8 + 255) / 256), dim3(256), 0, stream>>>(src, dst, n8, scale);
  };
  cvt(x,  xb, (size_t)SEQ * DMODEL, 1.0f);
  cvt(wq, wf, (size_t)QD * DMODEL, ASCALE);                              // rows 0..4095
  cvt(wk, wf + (size_t)QD * DMODEL, (size_t)KVD * DMODEL, 1.0f);         // rows 4096..5119
  cvt(wv, wf + (size_t)(QD + KVD) * DMODEL, (size_t)KVD * DMODEL, 1.0f); // rows 5120..6143
  cvt(wo, wob, (size_t)DMODEL * QD, 1.0f);

  k_qkv<<<dim3(256), dim3(512), 0, stream>>>(xb, wf, Qb, Kc, Vtg);

  k_rope<<<dim3(SEQ * NH * 64 / 256), 256, 0, stream>>>(Qb, fc, fs, NH);
  k_rope<<<dim3(SEQ * NKVH * 64 / 256), 256, 0, stream>>>(Kc, fc, fs, NKVH);

  k_flash<<<dim3(16, NH), 256, 0, stream>>>(Qb, Kc, Vtg, Ob);

  k_oproj<<<dim3(DMODEL / 256, SEQ / 128), dim3(512), 0, stream>>>(Ob, wob, out);
}

// Round 8
// 277.521 us; speedup vs baseline: 2.6941x; 1.0625x over previous
//
#include <hip/hip_runtime.h>
#include <hip/hip_bf16.h>
#include <stdint.h>

#define SEQ    2048
#define DMODEL 4096
#define NH     32
#define NKVH   8
#define HDIM   128
#define KVD    (NKVH*HDIM)   // 1024
#define QD     (NH*HDIM)     // 4096
#define QKVN   (QD + 2*KVD)  // 6144 fused projection columns
#define ASCALE 0.08838834764831845f

typedef __attribute__((ext_vector_type(8))) short s8v;   // 8 bf16
typedef __attribute__((ext_vector_type(4))) short s4v;   // 4 bf16
typedef __attribute__((ext_vector_type(4))) float f4v;   // 4 f32

#define MFMA16(acc, a, b) \
  asm("v_mfma_f32_16x16x32_bf16 %0, %1, %2, %0" : "+v"(acc) : "v"(a), "v"(b))

#define SBAR() do { __builtin_amdgcn_sched_barrier(0); \
                    __builtin_amdgcn_s_barrier();      \
                    __builtin_amdgcn_sched_barrier(0); } while (0)

__device__ __forceinline__ void gl2lds16(const void* g, void* l) {
  __builtin_amdgcn_global_load_lds(
      (const __attribute__((address_space(1))) void*)g,
      (__attribute__((address_space(3))) void*)l, 16, 0, 0);
}

// ---------------- merged f32 -> bf16 convert (5 regions, one launch) ----------------
// Region sizes (in 8-elem units) are compile-time multiples of 256 -> whole blocks
// are region-uniform, no divergence. wq gets ASCALE folded pre-round.
__global__ __launch_bounds__(256) void k_cvt5(const float* __restrict__ x,
                                              const float* __restrict__ wq,
                                              const float* __restrict__ wk,
                                              const float* __restrict__ wv,
                                              const float* __restrict__ wo,
                                              __hip_bfloat16* __restrict__ xb,
                                              __hip_bfloat16* __restrict__ wf,
                                              __hip_bfloat16* __restrict__ wob) {
  int i = blockIdx.x * 256 + threadIdx.x;
  const float* src;
  __hip_bfloat16* dst;
  float scale = 1.0f;
  if (i < 1048576)       { src = x;  dst = xb; }                                   // SEQ*DMODEL/8
  else if (i < 3145728)  { src = wq; dst = wf;  i -= 1048576; scale = ASCALE; }    // QD*DMODEL/8
  else if (i < 3670016)  { src = wk; dst = wf + (size_t)QD * DMODEL;  i -= 3145728; }
  else if (i < 4194304)  { src = wv; dst = wf + (size_t)(QD + KVD) * DMODEL; i -= 3670016; }
  else                   { src = wo; dst = wob; i -= 4194304; }
  const float4* p = (const float4*)src + (size_t)i * 2;
  float4 a = p[0], b = p[1];
  union { __hip_bfloat16 h[8]; s8v v; } o;
  o.h[0] = __float2bfloat16(a.x * scale); o.h[1] = __float2bfloat16(a.y * scale);
  o.h[2] = __float2bfloat16(a.z * scale); o.h[3] = __float2bfloat16(a.w * scale);
  o.h[4] = __float2bfloat16(b.x * scale); o.h[5] = __float2bfloat16(b.y * scale);
  o.h[6] = __float2bfloat16(b.z * scale); o.h[7] = __float2bfloat16(b.w * scale);
  *(s8v*)(dst + (size_t)i * 8) = o.v;
}

// ---------------- RoPE in-place on bf16 ----------------
__global__ __launch_bounds__(256) void k_rope(__hip_bfloat16* __restrict__ t,
                                              const float* __restrict__ fc,
                                              const float* __restrict__ fs, int heads) {
  int pid = blockIdx.x * 256 + threadIdx.x;
  int i = pid & 63;
  int rest = pid >> 6;
  int h = rest % heads;
  int s = rest / heads;
  size_t base = ((size_t)s * heads + h) * HDIM + 2 * i;
  uint32_t u = *(const uint32_t*)(t + base);
  __hip_bfloat16 hh[2]; *(uint32_t*)hh = u;
  float tr = __bfloat162float(hh[0]), ti = __bfloat162float(hh[1]);
  float c = fc[(size_t)s * 64 + i], sv = fs[(size_t)s * 64 + i];
  hh[0] = __float2bfloat16(tr * c - ti * sv);
  hh[1] = __float2bfloat16(tr * sv + ti * c);
  *(uint32_t*)(t + base) = *(uint32_t*)hh;
}

// ---------------- fused QKV projection: 4-phase counted-vmcnt 256x192 (R6, verified) ----------------
__global__ __launch_bounds__(512, 2) void k_qkv(const __hip_bfloat16* __restrict__ A,
                                                const __hip_bfloat16* __restrict__ W,
                                                __hip_bfloat16* __restrict__ Qb,
                                                __hip_bfloat16* __restrict__ Kc,
                                                __hip_bfloat16* __restrict__ Vt) {
  __shared__ __align__(16) __hip_bfloat16 sm[2][256 * 64 + 192 * 64];
  const int t5 = threadIdx.x;
  const int wave = t5 >> 6, lane = t5 & 63;
  const int lrow = lane & 15, kq = lane >> 4;
  const int wm = wave >> 2, wn = wave & 3;
  const int mt = blockIdx.x & 7, nt = blockIdx.x >> 3;
  const int m0 = mt * 256, n0 = nt * 192;

  auto stageA = [&](int p, int kt) {
#pragma unroll
    for (int it = 0; it < 4; ++it) {
      int chunk = it * 512 + t5;
      int r = chunk >> 3, cc = ((chunk & 7) ^ (r & 7)) * 8;
      gl2lds16(A + (size_t)(m0 + r) * DMODEL + kt * 64 + cc,
               (char*)&sm[p][0] + it * 8192 + wave * 1024);
    }
  };
  auto stageB = [&](int p, int kt) {
#pragma unroll
    for (int it = 0; it < 3; ++it) {
      int chunk = it * 512 + t5;
      int r = chunk >> 3, cc = ((chunk & 7) ^ (r & 7)) * 8;
      gl2lds16(W + (size_t)(n0 + r) * DMODEL + kt * 64 + cc,
               (char*)&sm[p][0] + 32768 + it * 8192 + wave * 1024);
    }
  };

  f4v acc[8][3] = {};

  stageA(0, 0); stageB(0, 0);
  stageA(1, 1); stageB(1, 1);

  const int NT = DMODEL / 64;
#pragma unroll 2
  for (int t = 0; t < NT; ++t) {
    const int p = t & 1;
    const __hip_bfloat16* As = &sm[p][0];
    const __hip_bfloat16* Bs = &sm[p][256 * 64];

    __builtin_amdgcn_sched_barrier(0);
    if (t == NT - 1) asm volatile("s_waitcnt vmcnt(0)" ::: "memory");
    else             asm volatile("s_waitcnt vmcnt(7)" ::: "memory");
    __builtin_amdgcn_s_barrier();
    __builtin_amdgcn_sched_barrier(0);

    s8v a0[8], b0[3];
#pragma unroll
    for (int m = 0; m < 8; ++m) {
      int row = wm * 128 + m * 16 + lrow;
      a0[m] = *(const s8v*)&As[row * 64 + ((kq * 8) ^ ((row & 7) << 3))];
    }
#pragma unroll
    for (int n = 0; n < 3; ++n) {
      int row = wn * 48 + n * 16 + lrow;
      b0[n] = *(const s8v*)&Bs[row * 64 + ((kq * 8) ^ ((row & 7) << 3))];
    }
    __builtin_amdgcn_s_setprio(1);
#pragma unroll
    for (int m = 0; m < 4; ++m)
#pragma unroll
      for (int n = 0; n < 3; ++n) MFMA16(acc[m][n], a0[m], b0[n]);
    __builtin_amdgcn_s_setprio(0);
    SBAR();

    s8v a1[8], b1[3];
#pragma unroll
    for (int m = 0; m < 8; ++m) {
      int row = wm * 128 + m * 16 + lrow;
      a1[m] = *(const s8v*)&As[row * 64 + ((32 + kq * 8) ^ ((row & 7) << 3))];
    }
#pragma unroll
    for (int n = 0; n < 3; ++n) {
      int row = wn * 48 + n * 16 + lrow;
      b1[n] = *(const s8v*)&Bs[row * 64 + ((32 + kq * 8) ^ ((row & 7) << 3))];
    }
    __builtin_amdgcn_s_setprio(1);
#pragma unroll
    for (int m = 4; m < 8; ++m)
#pragma unroll
      for (int n = 0; n < 3; ++n) MFMA16(acc[m][n], a0[m], b0[n]);
    __builtin_amdgcn_s_setprio(0);
    SBAR();

    if (t + 2 < NT) stageA(p, t + 2);
    __builtin_amdgcn_s_setprio(1);
#pragma unroll
    for (int m = 0; m < 4; ++m)
#pragma unroll
      for (int n = 0; n < 3; ++n) MFMA16(acc[m][n], a1[m], b1[n]);
    __builtin_amdgcn_s_setprio(0);
    SBAR();

    if (t + 2 < NT) stageB(p, t + 2);
    __builtin_amdgcn_s_setprio(1);
#pragma unroll
    for (int m = 4; m < 8; ++m)
#pragma unroll
      for (int n = 0; n < 3; ++n) MFMA16(acc[m][n], a1[m], b1[n]);
    __builtin_amdgcn_s_setprio(0);
  }

#pragma unroll
  for (int m = 0; m < 8; ++m)
#pragma unroll
    for (int n = 0; n < 3; ++n) {
      int c = n0 + wn * 48 + n * 16 + lrow;
      int r0 = m0 + wm * 128 + m * 16 + kq * 4;
      if (c < QD) {
#pragma unroll
        for (int j = 0; j < 4; ++j)
          Qb[(size_t)(r0 + j) * QD + c] = __float2bfloat16(acc[m][n][j]);
      } else if (c < QD + KVD) {
#pragma unroll
        for (int j = 0; j < 4; ++j)
          Kc[(size_t)(r0 + j) * KVD + (c - QD)] = __float2bfloat16(acc[m][n][j]);
      } else {
        union { __hip_bfloat16 b[4]; s4v v; } u;
#pragma unroll
        for (int j = 0; j < 4; ++j) u.b[j] = __float2bfloat16(acc[m][n][j]);
        *(s4v*)&Vt[(size_t)(c - QD - KVD) * SEQ + r0] = u.v;
      }
    }
}

// ---------------- O-projection: 4-phase counted-vmcnt 128x256 (R7, verified) ----------------
__global__ __launch_bounds__(512, 2) void k_oproj(const __hip_bfloat16* __restrict__ A,
                                                  const __hip_bfloat16* __restrict__ B,
                                                  float* __restrict__ C) {
  __shared__ __align__(16) __hip_bfloat16 sm[2][128 * 64 + 256 * 64];
  const int t5 = threadIdx.x;
  const int wave = t5 >> 6, lane = t5 & 63;
  const int lrow = lane & 15, kq = lane >> 4;
  const int wm = wave >> 2, wn = wave & 3;
  const int m0 = blockIdx.y * 128, n0 = blockIdx.x * 256;

  auto stageA = [&](int p, int kt) {
#pragma unroll
    for (int it = 0; it < 2; ++it) {
      int chunk = it * 512 + t5;
      int r = chunk >> 3, cc = ((chunk & 7) ^ (r & 7)) * 8;
      gl2lds16(A + (size_t)(m0 + r) * QD + kt * 64 + cc,
               (char*)&sm[p][0] + it * 8192 + wave * 1024);
    }
  };
  auto stageB = [&](int p, int kt) {
#pragma unroll
    for (int it = 0; it < 4; ++it) {
      int chunk = it * 512 + t5;
      int r = chunk >> 3, cc = ((chunk & 7) ^ (r & 7)) * 8;
      gl2lds16(B + (size_t)(n0 + r) * QD + kt * 64 + cc,
               (char*)&sm[p][0] + 16384 + it * 8192 + wave * 1024);
    }
  };

  f4v acc[4][4] = {};

  stageA(0, 0); stageB(0, 0);
  stageA(1, 1); stageB(1, 1);

  const int NT = QD / 64;
#pragma unroll 2
  for (int t = 0; t < NT; ++t) {
    const int p = t & 1;
    const __hip_bfloat16* As = &sm[p][0];
    const __hip_bfloat16* Bs = &sm[p][128 * 64];

    __builtin_amdgcn_sched_barrier(0);
    if (t == NT - 1) asm volatile("s_waitcnt vmcnt(0)" ::: "memory");
    else             asm volatile("s_waitcnt vmcnt(6)" ::: "memory");
    __builtin_amdgcn_s_barrier();
    __builtin_amdgcn_sched_barrier(0);

    s8v a0[4], b0[4];
#pragma unroll
    for (int m = 0; m < 4; ++m) {
      int row = wm * 64 + m * 16 + lrow;
      a0[m] = *(const s8v*)&As[row * 64 + ((kq * 8) ^ ((row & 7) << 3))];
    }
#pragma unroll
    for (int n = 0; n < 4; ++n) {
      int row = wn * 64 + n * 16 + lrow;
      b0[n] = *(const s8v*)&Bs[row * 64 + ((kq * 8) ^ ((row & 7) << 3))];
    }
    __builtin_amdgcn_s_setprio(1);
#pragma unroll
    for (int m = 0; m < 2; ++m)
#pragma unroll
      for (int n = 0; n < 4; ++n) MFMA16(acc[m][n], a0[m], b0[n]);
    __builtin_amdgcn_s_setprio(0);
    SBAR();

    s8v a1[4], b1[4];
#pragma unroll
    for (int m = 0; m < 4; ++m) {
      int row = wm * 64 + m * 16 + lrow;
      a1[m] = *(const s8v*)&As[row * 64 + ((32 + kq * 8) ^ ((row & 7) << 3))];
    }
#pragma unroll
    for (int n = 0; n < 4; ++n) {
      int row = wn * 64 + n * 16 + lrow;
      b1[n] = *(const s8v*)&Bs[row * 64 + ((32 + kq * 8) ^ ((row & 7) << 3))];
    }
    __builtin_amdgcn_s_setprio(1);
#pragma unroll
    for (int m = 2; m < 4; ++m)
#pragma unroll
      for (int n = 0; n < 4; ++n) MFMA16(acc[m][n], a0[m], b0[n]);
    __builtin_amdgcn_s_setprio(0);
    SBAR();

    if (t + 2 < NT) stageA(p, t + 2);
    __builtin_amdgcn_s_setprio(1);
#pragma unroll
    for (int m = 0; m < 2; ++m)
#pragma unroll
      for (int n = 0; n < 4; ++n) MFMA16(acc[m][n], a1[m], b1[n]);
    __builtin_amdgcn_s_setprio(0);
    SBAR();

    if (t + 2 < NT) stageB(p, t + 2);
    __builtin_amdgcn_s_setprio(1);
#pragma unroll
    for (int m = 2; m < 4; ++m)
#pragma unroll
      for (int n = 0; n < 4; ++n) MFMA16(acc[m][n], a1[m], b1[n]);
    __builtin_amdgcn_s_setprio(0);
  }

#pragma unroll
  for (int m = 0; m < 4; ++m)
#pragma unroll
    for (int n = 0; n < 4; ++n)
#pragma unroll
      for (int j = 0; j < 4; ++j) {
        int r = m0 + wm * 64 + m * 16 + kq * 4 + j;
        int c = n0 + wn * 64 + n * 16 + lrow;
        C[(size_t)r * DMODEL + c] = acc[m][n][j];
      }
}

// ---------------- causal flash attention: swapped-QK^T in-lane softmax ----------------
// S^T = mfma(K_frag, Q_frag): lane (lrow,kq) holds S[k = n*16+kq*4+j][q = lrow].
// Row-softmax is 15 local fmax + 2 shfl_xor; P written as 4x ds_write_b64
// (k-consecutive j), lrow-keyed XOR swizzle matching the PV b128 read.
// All values bit-identical to R7 (same products, same fp order per element).
__global__ __launch_bounds__(256, 2) void k_flash(const __hip_bfloat16* __restrict__ Q,
                                                  const __hip_bfloat16* __restrict__ Kb,
                                                  const __hip_bfloat16* __restrict__ Vtg,
                                                  __hip_bfloat16* __restrict__ O) {
  __shared__ __align__(16) __hip_bfloat16 Ks[2][64 * 128];
  __shared__ __align__(16) __hip_bfloat16 Vs[144 * 64];   // rows 128..143 = ones
  __shared__ __align__(16) __hip_bfloat16 Ps[4][16 * 64];
  const int qp = blockIdx.x, h = blockIdx.y, g = h >> 2;
  const int t = threadIdx.x, wave = t >> 6, lane = t & 63;
  const int lrow = lane & 15, kq = lane >> 4;
  const int qtA = qp, qtB = 31 - qp;

  s8v qfA[4], qfB[4];
  {
    const int qrA = qtA * 64 + wave * 16 + lrow;
    const int qrB = qtB * 64 + wave * 16 + lrow;
#pragma unroll
    for (int tt = 0; tt < 4; ++tt) {
      qfA[tt] = *(const s8v*)(Q + (size_t)qrA * QD + h * HDIM + tt * 32 + kq * 8);
      qfB[tt] = *(const s8v*)(Q + (size_t)qrB * QD + h * HDIM + tt * 32 + kq * 8);
    }
  }

  if (t < 128) {
    union { __hip_bfloat16 h8[8]; s8v v; } one;
#pragma unroll
    for (int e = 0; e < 8; ++e) one.h8[e] = __float2bfloat16(1.0f);
    *(s8v*)&Vs[128 * 64 + t * 8] = one.v;
  }

  f4v oA[9] = {}, oB[9] = {};   // [8] = l accumulator (ones-column)
  float mA = -1e30f, mB = -1e30f;

  auto stage_k = [&](int buf, int kv) {
#pragma unroll
    for (int it = 0; it < 4; ++it) {
      int chunk = it * 256 + t;
      int r = chunk >> 4, cc = ((chunk & 15) ^ (r & 7)) * 8;
      gl2lds16(Kb + (size_t)(kv * 64 + r) * KVD + g * HDIM + cc,
               (char*)&Ks[buf][0] + it * 4096 + wave * 1024);
    }
  };
  auto stage_v = [&](int kv) {
#pragma unroll
    for (int it = 0; it < 4; ++it) {
      int chunk = it * 256 + t;
      int d = chunk >> 3, cc = ((chunk & 7) ^ (d & 7)) * 8;
      gl2lds16(Vtg + (size_t)(g * HDIM + d) * SEQ + kv * 64 + cc,
               (char*)Vs + it * 4096 + wave * 1024);
    }
  };

  // softmax + PV for one tile-job; s[n][j] = S[kv*64+n*16+kq*4+j][q=lrow] (scaled)
  auto soft_pv = [&](f4v (&s)[4], int qt, int kv, f4v (&acc_o)[9], float& mrun) {
    __hip_bfloat16* P = &Ps[wave][0];
    const bool diag = (kv == qt);
    const int qi = qt * 64 + wave * 16 + lrow;   // this lane's q-row
    const int swz = (lrow & 7) << 3;
    float pv[4][4];
    float mx = -1e30f;
#pragma unroll
    for (int n = 0; n < 4; ++n)
#pragma unroll
      for (int j = 0; j < 4; ++j) {
        float v = s[n][j];
        if (diag) {
          int ki = kv * 64 + n * 16 + kq * 4 + j;
          if (ki > qi) v = -1e30f;
        }
        pv[n][j] = v;
        mx = fmaxf(mx, v);
      }
    mx = fmaxf(mx, __shfl_xor(mx, 16, 64));
    mx = fmaxf(mx, __shfl_xor(mx, 32, 64));
    if (!__all(mx <= mrun)) {        // else fsc==1 exactly for every lane -> elide
      float mnew = fmaxf(mrun, mx);
      float fsc = __expf(mrun - mnew);
      mrun = mnew;
      float fj[4];                   // acc_o rows are q = kq*4+j -> fetch their fsc
#pragma unroll
      for (int j = 0; j < 4; ++j) fj[j] = __shfl(fsc, kq * 4 + j, 64);
#pragma unroll
      for (int n = 0; n < 9; ++n) {
        acc_o[n][0] *= fj[0]; acc_o[n][1] *= fj[1];
        acc_o[n][2] *= fj[2]; acc_o[n][3] *= fj[3];
      }
    }
    asm volatile("" ::: "memory");
#pragma unroll
    for (int n = 0; n < 4; ++n) {
      union { __hip_bfloat16 b[4]; s4v v; } u;
#pragma unroll
      for (int j = 0; j < 4; ++j) u.b[j] = __float2bfloat16(__expf(pv[n][j] - mrun));
      *(s4v*)&P[lrow * 64 + ((n * 16 + kq * 4) ^ swz)] = u.v;   // k-consecutive b64
    }
    asm volatile("" ::: "memory");
#pragma unroll
    for (int tt = 0; tt < 2; ++tt) {
      s8v pa = *(const s8v*)&P[lrow * 64 + ((tt * 32 + kq * 8) ^ swz)];
#pragma unroll
      for (int n = 0; n < 9; ++n) {          // n==8: ones rows -> l accumulation
        int d = n * 16 + lrow;
        s8v vf = *(const s8v*)&Vs[d * 64 + ((tt * 32 + kq * 8) ^ ((d & 7) << 3))];
        MFMA16(acc_o[n], pa, vf);
      }
    }
  };

  stage_k(0, 0);
  int cur = 0;
  for (int kv = 0; kv <= qtB; ++kv) {
    const bool actA = (kv <= qtA);
    __syncthreads();
    if (kv < qtB) stage_k(cur ^ 1, kv + 1);
    stage_v(kv);

    // S^T = K * Q^T (operand-swapped MFMA; same Ks reads as before)
    f4v sB[4] = {}, sA[4] = {};
    if (actA) {
#pragma unroll
      for (int tt = 0; tt < 4; ++tt)
#pragma unroll
        for (int n = 0; n < 4; ++n) {
          int row = n * 16 + lrow;
          s8v kf = *(const s8v*)&Ks[cur][row * 128 + ((tt * 32 + kq * 8) ^ ((row & 7) << 3))];
          MFMA16(sB[n], kf, qfB[tt]);
          MFMA16(sA[n], kf, qfA[tt]);
        }
    } else {
#pragma unroll
      for (int tt = 0; tt < 4; ++tt)
#pragma unroll
        for (int n = 0; n < 4; ++n) {
          int row = n * 16 + lrow;
          s8v kf = *(const s8v*)&Ks[cur][row * 128 + ((tt * 32 + kq * 8) ^ ((row & 7) << 3))];
          MFMA16(sB[n], kf, qfB[tt]);
        }
    }
    __syncthreads();

    soft_pv(sB, qtB, kv, oB, mB);
    if (actA) soft_pv(sA, qtA, kv, oA, mA);
    cur ^= 1;
  }

#pragma unroll
  for (int n = 0; n < 8; ++n)
#pragma unroll
    for (int j = 0; j < 4; ++j) {
      int d = n * 16 + lrow;
      int qiB = qtB * 64 + wave * 16 + kq * 4 + j;
      O[(size_t)qiB * QD + h * HDIM + d] = __float2bfloat16(oB[n][j] / oB[8][j]);
      int qiA = qtA * 64 + wave * 16 + kq * 4 + j;
      O[(size_t)qiA * QD + h * HDIM + d] = __float2bfloat16(oA[n][j] / oA[8][j]);
    }
}

// ---------------- launch ----------------
extern "C" void kernel_launch(void* const* d_in, const int* in_sizes, int n_in,
                              void* d_out, int out_size, void* d_ws, size_t ws_size,
                              hipStream_t stream) {
  const float* x  = (const float*)d_in[0];
  const float* fc = (const float*)d_in[1];
  const float* fs = (const float*)d_in[2];
  const float* wq = (const float*)d_in[3];
  const float* wk = (const float*)d_in[4];
  const float* wv = (const float*)d_in[5];
  const float* wo = (const float*)d_in[6];
  float* out = (float*)d_out;

  char* ws = (char*)d_ws;
  auto alloc = [&](size_t bytes) {
    char* p = ws;
    ws += (bytes + 255) & ~(size_t)255;
    return p;
  };
  __hip_bfloat16* xb  = (__hip_bfloat16*)alloc((size_t)SEQ * DMODEL * 2);
  __hip_bfloat16* wf  = (__hip_bfloat16*)alloc((size_t)QKVN * DMODEL * 2);
  __hip_bfloat16* wob = (__hip_bfloat16*)alloc((size_t)DMODEL * QD * 2);
  __hip_bfloat16* Qb  = (__hip_bfloat16*)alloc((size_t)SEQ * QD * 2);
  __hip_bfloat16* Kc  = (__hip_bfloat16*)alloc((size_t)SEQ * KVD * 2);
  __hip_bfloat16* Vtg = (__hip_bfloat16*)alloc((size_t)KVD * SEQ * 2);
  __hip_bfloat16* Ob  = (__hip_bfloat16*)alloc((size_t)SEQ * QD * 2);

  // one merged conversion launch (6291456 8-elem units / 256 = 24576 blocks)
  k_cvt5<<<dim3(24576), dim3(256), 0, stream>>>(x, wq, wk, wv, wo, xb, wf, wob);

  k_qkv<<<dim3(256), dim3(512), 0, stream>>>(xb, wf, Qb, Kc, Vtg);

  k_rope<<<dim3(SEQ * NH * 64 / 256), 256, 0, stream>>>(Qb, fc, fs, NH);
  k_rope<<<dim3(SEQ * NKVH * 64 / 256), 256, 0, stream>>>(Kc, fc, fs, NKVH);

  k_flash<<<dim3(16, NH), 256, 0, stream>>>(Qb, Kc, Vtg, Ob);

  k_oproj<<<dim3(DMODEL / 256, SEQ / 128), dim3(512), 0, stream>>>(Ob, wob, out);
}